// Round 7
// baseline (11355.079 us; speedup 1.0000x reference)
//
#include <hip/hip_runtime.h>

// GRU_781684048417 — round 12: r11 + same-lag staging overlap.
//
// r11 = r9 protocol + XG precompute, 9.30ms, stable.  Per-link 13.3us =
// 5.1 VALU + ~4.3 LDS (overlapped) + exposed stage-RTT/polls.  This round
// hides the stage RTT under the hh gemm WITHOUT changing lag or pollers
// (r10's regression came from lag-2 polls + 512-thread CP polling — avoided):
//  - stacks 1/3: polls(8thr,lag-1) -> barrier -> ASYNC stage loads to regs ->
//    hh gemm (covers RTT) -> vmcnt(0) + land -> barrier -> ih gemm.
//  - stack 2: all polls (sibling t / parent t+1 / child t-3) consolidated at
//    step start (disjoint thread groups); ih-kt0 32KB stage prefetched into
//    16 VGPR across the whole hh phase; ih-kt1 unchanged.
// Everything else byte-identical to r11 (probes, fast/slow links, XG, flags).

#define TPB 512
#define DRING 4
#define FS 64                       // ints per flag/probe slot (256 B)
#define PROBE_A 0x51CAFE77
#define PROBE_B 0x2B2B2B2B

typedef float vf4 __attribute__((ext_vector_type(4)));

__device__ __forceinline__ float sigmoid_f(float x) { return 1.0f / (1.0f + __expf(-x)); }
__device__ __forceinline__ float tanh_f(float x)    { return 1.0f - 2.0f / (__expf(2.0f * x) + 1.0f); }

// ---- coherence-point flag ops: relaxed agent-scope atomics ----
__device__ __forceinline__ int cp_load(const int* p) {
    return __hip_atomic_load(p, __ATOMIC_RELAXED, __HIP_MEMORY_SCOPE_AGENT);
}
__device__ __forceinline__ void cp_store(int* p, int v) {
    __hip_atomic_store(p, v, __ATOMIC_RELAXED, __HIP_MEMORY_SCOPE_AGENT);
}
__device__ __forceinline__ int cp_poll_nz(const int* p) {
    int v;
    while (!(v = cp_load(p))) __builtin_amdgcn_s_sleep(8);
    return v;
}

// ---- intra-XCD (shared L2) ops: sc0 = bypass L1, service at XCD L2 ----
__device__ __forceinline__ void vmwait0() { asm volatile("s_waitcnt vmcnt(0)" ::: "memory"); }
__device__ __forceinline__ int ld_l2_b32_wait(const int* p) {
    int r;
    asm volatile("global_load_dword %0, %1, off sc0\n\t"
                 "s_waitcnt vmcnt(0)"
                 : "=v"(r) : "v"(p) : "memory");
    return r;
}
__device__ __forceinline__ void st_l2_b32(int* p, int v) {
    asm volatile("global_store_dword %0, %1, off sc0" :: "v"(p), "v"(v) : "memory");
}
__device__ __forceinline__ void st_l2_f4(float* p, float4 v) {
    vf4 w; w[0] = v.x; w[1] = v.y; w[2] = v.z; w[3] = v.w;
    asm volatile("global_store_dwordx4 %0, %1, off sc0" :: "v"(p), "v"(w) : "memory");
}
__device__ __forceinline__ void ld_l2_2xf4(const float* p0, const float* p1,
                                           vf4& a, vf4& b) {
    asm volatile("global_load_dwordx4 %0, %2, off sc0\n\t"
                 "global_load_dwordx4 %1, %3, off sc0\n\t"
                 "s_waitcnt vmcnt(0)"
                 : "=&v"(a), "=&v"(b)
                 : "v"(p0), "v"(p1)
                 : "memory");
}
__device__ __forceinline__ void ld_l2_4xf4(const float* p0, const float* p1,
                                           const float* p2, const float* p3,
                                           vf4& a, vf4& b, vf4& c, vf4& d) {
    asm volatile("global_load_dwordx4 %0, %4, off sc0\n\t"
                 "global_load_dwordx4 %1, %5, off sc0\n\t"
                 "global_load_dwordx4 %2, %6, off sc0\n\t"
                 "global_load_dwordx4 %3, %7, off sc0\n\t"
                 "s_waitcnt vmcnt(0)"
                 : "=&v"(a), "=&v"(b), "=&v"(c), "=&v"(d)
                 : "v"(p0), "v"(p1), "v"(p2), "v"(p3)
                 : "memory");
}

// ---- cross-XCD (coherence-point) wide ops: sc0 sc1 = bypass L1 AND L2 ----
__device__ __forceinline__ void st_cp_f4(float* p, float4 v) {
    vf4 w; w[0] = v.x; w[1] = v.y; w[2] = v.z; w[3] = v.w;
    asm volatile("global_store_dwordx4 %0, %1, off sc0 sc1" :: "v"(p), "v"(w) : "memory");
}
__device__ __forceinline__ void ld_cp_2xf4(const float* p0, const float* p1,
                                           vf4& a, vf4& b) {
    asm volatile("global_load_dwordx4 %0, %2, off sc0 sc1\n\t"
                 "global_load_dwordx4 %1, %3, off sc0 sc1\n\t"
                 "s_waitcnt vmcnt(0)"
                 : "=&v"(a), "=&v"(b)
                 : "v"(p0), "v"(p1)
                 : "memory");
}
__device__ __forceinline__ void ld_cp_4xf4(const float* p0, const float* p1,
                                           const float* p2, const float* p3,
                                           vf4& a, vf4& b, vf4& c, vf4& d) {
    asm volatile("global_load_dwordx4 %0, %4, off sc0 sc1\n\t"
                 "global_load_dwordx4 %1, %5, off sc0 sc1\n\t"
                 "global_load_dwordx4 %2, %6, off sc0 sc1\n\t"
                 "global_load_dwordx4 %3, %7, off sc0 sc1\n\t"
                 "s_waitcnt vmcnt(0)"
                 : "=&v"(a), "=&v"(b), "=&v"(c), "=&v"(d)
                 : "v"(p0), "v"(p1), "v"(p2), "v"(p3)
                 : "memory");
}

// ---- ASYNC issue (no internal wait); drained by a later vmwait0 ----
__device__ __forceinline__ void ld_l2_2xf4_async(const float* p0, const float* p1,
                                                 vf4& a, vf4& b) {
    asm volatile("global_load_dwordx4 %0, %2, off sc0\n\t"
                 "global_load_dwordx4 %1, %3, off sc0"
                 : "=&v"(a), "=&v"(b)
                 : "v"(p0), "v"(p1)
                 : "memory");
}
__device__ __forceinline__ void ld_cp_2xf4_async(const float* p0, const float* p1,
                                                 vf4& a, vf4& b) {
    asm volatile("global_load_dwordx4 %0, %2, off sc0 sc1\n\t"
                 "global_load_dwordx4 %1, %3, off sc0 sc1"
                 : "=&v"(a), "=&v"(b)
                 : "v"(p0), "v"(p1)
                 : "memory");
}
__device__ __forceinline__ void ld_l2_4xf4_async(const float* p0, const float* p1,
                                                 const float* p2, const float* p3,
                                                 vf4& a, vf4& b, vf4& c, vf4& d) {
    asm volatile("global_load_dwordx4 %0, %4, off sc0\n\t"
                 "global_load_dwordx4 %1, %5, off sc0\n\t"
                 "global_load_dwordx4 %2, %6, off sc0\n\t"
                 "global_load_dwordx4 %3, %7, off sc0"
                 : "=&v"(a), "=&v"(b), "=&v"(c), "=&v"(d)
                 : "v"(p0), "v"(p1), "v"(p2), "v"(p3)
                 : "memory");
}
__device__ __forceinline__ void ld_cp_4xf4_async(const float* p0, const float* p1,
                                                 const float* p2, const float* p3,
                                                 vf4& a, vf4& b, vf4& c, vf4& d) {
    asm volatile("global_load_dwordx4 %0, %4, off sc0 sc1\n\t"
                 "global_load_dwordx4 %1, %5, off sc0 sc1\n\t"
                 "global_load_dwordx4 %2, %6, off sc0 sc1\n\t"
                 "global_load_dwordx4 %3, %7, off sc0 sc1"
                 : "=&v"(a), "=&v"(b), "=&v"(c), "=&v"(d)
                 : "v"(p0), "v"(p1), "v"(p2), "v"(p3)
                 : "memory");
}

__device__ __forceinline__ void wait_flag(int* fp, int tgt, bool fast) {
    if (fast) { while (ld_l2_b32_wait(fp) < tgt) __builtin_amdgcn_s_sleep(1); }
    else      { while (cp_load(fp) < tgt)        __builtin_amdgcn_s_sleep(2); }
}

struct PassArgs {
    const float* wih0; const float* bih0; const float* whh0; const float* bhh0;
    const float* wihA; const float* bihA; const float* whhA; const float* bhhA;
    int firstLayer;
    int NL;
    const float* seqIn;
    long seqTs;
    float* seqOut;
    float* hFinal;
    float* rings;            // [192][DRING][4096]
    int* done;               // [192][FS]
    int* prb;                // [192][FS] probe slots
    const float* xg;         // [96][NGtot][128] precomputed layer-0 ih gates
};

template<int STACK>
__global__ __launch_bounds__(TPB, 2) void pass_kernel(PassArgs A)
{
    constexpr int NG    = (STACK == 2) ? 96 : 192;   // gate rows per block
    constexpr int NB    = (STACK == 2) ? 128 : 64;   // batch rows per block
    constexpr int KH    = (STACK == 2) ? 128 : 64;   // recurrent K
    constexpr int KI    = (STACK == 2) ? 128 : 64;   // input K (l>0)
    constexpr int PARTS = (STACK == 2) ? 4 : 2;
    constexpr int JS    = NG / 3;
    constexpr int NGG   = NG / 6;
    constexpr int WROW  = NGG * 12;                  // packed floats per k-pair
    constexpr int XGT   = (STACK == 2) ? 384 * 128 : 192 * 128;

    // packed weights: [k/2][gg][12] = R0 R1 Z0 Z1 N0 N1 (k) | same (k+1)
    __shared__ __align__(16) float wt_hh[(KH / 2) * WROW];
    __shared__ __align__(16) float wt_ih[(KI / 2) * WROW];
    __shared__ __align__(16) float atile[64 * NB];
    __shared__ __align__(16) float hbuf[64 * 64];

    const int tid  = threadIdx.x;

    // layer->blockIdx swizzle (XCD grouping heuristic; probes carry correctness)
    const int bidx = blockIdx.x;
    int l, part;
    if (STACK == 2) { l = 6  * (bidx & 7) + ((bidx >> 3) >> 2); part = (bidx >> 3) & 3; }
    else            { l = 12 * (bidx & 7) + ((bidx >> 3) >> 1); part = (bidx >> 3) & 1; }
    const int rb = l * PARTS + part;
    const int gl = A.firstLayer + l;

    const int gg = tid & (NGG - 1);
    const int bg = tid / NGG;
    const int jl0 = 2 * gg, jl1 = 2 * gg + 1;
    const int b0 = 4 * bg;

    const float *wih, *bih, *whh, *bhh;
    if (gl == 0) { wih = A.wih0; bih = A.bih0; whh = A.whh0; bhh = A.bhh0; }
    else {
        const int wsz = (STACK == 2) ? 384 * 128 : 192 * 64;
        const int bs  = (STACK == 2) ? 384 : 192;
        wih = A.wihA + (size_t)(gl - 1) * wsz; bih = A.bihA + (size_t)(gl - 1) * bs;
        whh = A.whhA + (size_t)(gl - 1) * wsz; bhh = A.bhhA + (size_t)(gl - 1) * bs;
    }

    auto grow = [&](int r) -> int {
        if (STACK == 2) return (r >> 5) * 128 + 32 * part + (r & 31);
        return r;
    };

    // ---- packed weight fills (wt_ih only for l>0; l==0 uses XG) ----
    for (int i = tid; i < NG * KH; i += TPB) {
        int r = i / KH, k = i - r * KH;
        int g = r / JS, j = r - g * JS;
        wt_hh[(k >> 1) * WROW + (j >> 1) * 12 + (k & 1) * 6 + g * 2 + (j & 1)]
            = whh[(size_t)grow(r) * KH + k];
    }
    if (l > 0) {
        for (int i = tid; i < NG * KI; i += TPB) {
            int r = i / KI, k = i - r * KI;
            int g = r / JS, j = r - g * JS;
            wt_ih[(k >> 1) * WROW + (j >> 1) * 12 + (k & 1) * 6 + g * 2 + (j & 1)]
                = wih[(size_t)grow(r) * KI + k];
        }
    }

    float bR[2], bZ[2], bNH[2], bNI[2];
#pragma unroll
    for (int jj = 0; jj < 2; ++jj) {
        int jl = jl0 + jj;
        bR[jj]  = bhh[grow(jl)]          + bih[grow(jl)];
        bZ[jj]  = bhh[grow(JS + jl)]     + bih[grow(JS + jl)];
        bNH[jj] = bhh[grow(2 * JS + jl)];
        bNI[jj] = bih[grow(2 * JS + jl)];
    }

    float hprev[2][4];
#pragma unroll
    for (int jj = 0; jj < 2; ++jj)
#pragma unroll
        for (int bb = 0; bb < 4; ++bb) hprev[jj][bb] = 0.0f;

    // ---------------- one-time L2-sharing probes + link modes ----------------
    bool f_in = false, f_out = false, f_fl_self = false, f_fl_par = false, f_fl_child = false;
    {
        int* hsk = (int*)atile;
        const int NL = A.NL;
        if (STACK != 2) {
            if (tid == 0 && l < NL - 1) {
                int* rg = A.prb + (size_t)rb * FS;
                cp_store(rg, PROBE_A); vmwait0();
                (void)ld_l2_b32_wait(rg);
                cp_store(rg, PROBE_B); vmwait0();
                cp_store(rg + 1, 1);
            }
            if (tid == 1 && l > 0) {
                int* rg = A.prb + (size_t)((l - 1) * PARTS + part) * FS;
                (void)cp_poll_nz(rg + 1);
                int v = ld_l2_b32_wait(rg);
                cp_store(rg + 2, (v == PROBE_A) ? 2 : 1);
            }
            if (tid >= 8 && tid < 12) {
                int j = l - 2 + (tid - 8);
                hsk[tid - 8] = (j >= 0 && j < NL - 1)
                    ? cp_poll_nz(A.prb + (size_t)(j * PARTS + part) * FS + 2) : 0;
            }
        } else {
            if (part == 0 && tid < 4 && (tid > 0 || l < NL - 1)) {
                int* rg = A.prb + (size_t)(l * 4 + tid) * FS;
                cp_store(rg, PROBE_A); vmwait0();
                (void)ld_l2_b32_wait(rg);
                cp_store(rg, PROBE_B); vmwait0();
                cp_store(rg + 1, 1);
            }
            if (tid == 4 && (part != 0 || l > 0)) {
                int* rg = (part != 0) ? A.prb + (size_t)(l * 4 + part) * FS
                                      : A.prb + (size_t)((l - 1) * 4) * FS;
                (void)cp_poll_nz(rg + 1);
                int v = ld_l2_b32_wait(rg);
                cp_store(rg + 2, (v == PROBE_A) ? 2 : 1);
            }
            if (tid >= 8 && tid < 28) {
                int q = tid - 8, r = q >> 2, p = q & 3;
                int a = l - 2 + r;
                bool valid = (a >= 0 && a < NL) && (p > 0 || a < NL - 1);
                hsk[q] = valid ? cp_poll_nz(A.prb + (size_t)(a * 4 + p) * FS + 2) : 0;
            }
        }
        __syncthreads();
        if (STACK != 2) {
            const int NLl = A.NL;
            bool pp0 = hsk[0] == 2, pp1 = hsk[1] == 2, pp2 = hsk[2] == 2, pp3 = hsk[3] == 2;
            f_in       = (l > 0) && pp1;
            f_out      = (l == NLl - 1) || pp2;
            f_fl_self  = (l == 0 || pp1) && (l == NLl - 1 || pp2);
            f_fl_par   = (l > 0) && pp1 && (l < 2 || pp0);
            f_fl_child = (l < NLl - 1) && pp2 && (l + 2 >= NLl || pp3);
        } else {
            const int NLl = A.NL;
            bool S[5], T[4];
#pragma unroll
            for (int r = 0; r < 5; ++r)
                S[r] = hsk[r * 4 + 1] == 2 && hsk[r * 4 + 2] == 2 && hsk[r * 4 + 3] == 2;
#pragma unroll
            for (int r = 0; r < 4; ++r) T[r] = hsk[r * 4 + 0] == 2;
            f_out      = S[2] && (l == NLl - 1 || (S[3] && T[2]));
            f_in       = (l > 0) && S[1] && S[2] && T[1];
            f_fl_self  = S[2] && (l == 0 || (S[1] && T[1])) && (l == NLl - 1 || (S[3] && T[2]));
            f_fl_par   = (l > 0) && S[1] && S[2] && T[1] && (l < 2 || (S[0] && T[0]));
            f_fl_child = (l < NLl - 1) && S[2] && S[3] && T[2] && (l + 2 >= NLl || (S[4] && T[3]));
        }
        __syncthreads();
    }

    // packed gemm: 32 k-pairs = 64 k per call.
    auto gemmP = [&](const float* wt, const float* at, int astride,
                     float (&accR)[2][4], float (&accZ)[2][4], float (&accN)[2][4]) {
#pragma unroll 2
        for (int k2 = 0; k2 < 32; ++k2) {
            const float* wr = wt + k2 * WROW + gg * 12;
            vf4 q0 = *(const vf4*)(wr);
            vf4 q1 = *(const vf4*)(wr + 4);
            vf4 q2 = *(const vf4*)(wr + 8);
            const float* ar = at + (2 * k2) * astride + b0;
            float4 a0v = *(const float4*)(ar);
            float4 a1v = *(const float4*)(ar + astride);
            float a0[4] = {a0v.x, a0v.y, a0v.z, a0v.w};
            float a1[4] = {a1v.x, a1v.y, a1v.z, a1v.w};
#pragma unroll
            for (int bb = 0; bb < 4; ++bb) {
                accR[0][bb] += q0.x * a0[bb];  accR[1][bb] += q0.y * a0[bb];
                accZ[0][bb] += q0.z * a0[bb];  accZ[1][bb] += q0.w * a0[bb];
                accN[0][bb] += q1.x * a0[bb];  accN[1][bb] += q1.y * a0[bb];
                accR[0][bb] += q1.z * a1[bb];  accR[1][bb] += q1.w * a1[bb];
                accZ[0][bb] += q2.x * a1[bb];  accZ[1][bb] += q2.y * a1[bb];
                accN[0][bb] += q2.z * a1[bb];  accN[1][bb] += q2.w * a1[bb];
            }
        }
    };

    // STACK2 ring staging (8192 floats per kt, 128-wide rows)
    auto stage2_addr = [&](int baseBlk, int slotT, int kt, int q) -> const float* {
        int u4 = tid + q * TPB, r = u4 >> 5, c4 = u4 & 31, kk = kt * 64 + r;
        return A.rings + ((size_t)(baseBlk + (kk >> 5)) * DRING + slotT) * 4096
                       + (kk & 31) * 128 + 4 * c4;
    };
    auto stage2_land = [&](vf4 ta, vf4 tb, vf4 tc, vf4 td) {
        int u4, r, c4;
        u4 = tid;           r = u4 >> 5; c4 = u4 & 31; *(vf4*)&atile[r * 128 + 4 * c4] = ta;
        u4 = tid + TPB;     r = u4 >> 5; c4 = u4 & 31; *(vf4*)&atile[r * 128 + 4 * c4] = tb;
        u4 = tid + 2 * TPB; r = u4 >> 5; c4 = u4 & 31; *(vf4*)&atile[r * 128 + 4 * c4] = tc;
        u4 = tid + 3 * TPB; r = u4 >> 5; c4 = u4 & 31; *(vf4*)&atile[r * 128 + 4 * c4] = td;
    };
    auto stage2 = [&](int baseBlk, int slotT, int kt, bool fast) {
        const float* p[4];
#pragma unroll
        for (int q = 0; q < 4; ++q) p[q] = stage2_addr(baseBlk, slotT, kt, q);
        vf4 ta, tb, tc, td;
        if (fast) ld_l2_4xf4(p[0], p[1], p[2], p[3], ta, tb, tc, td);
        else      ld_cp_4xf4(p[0], p[1], p[2], p[3], ta, tb, tc, td);
        stage2_land(ta, tb, tc, td);
    };

    for (int t = 0; t < 96; ++t) {
        float accR[2][4] = {}, accZ[2][4] = {}, accNH[2][4] = {}, accNI[2][4] = {};

        if (STACK != 2) {
            // ---- polls first (8 threads, lag-1 targets as r11) ----
            if (tid < 8) {
                int grp = tid >> 2, idx = tid & 3;
                int* fp = nullptr; int tgt = 0; bool fm = false;
                if (grp == 0) { if (l > 0 && idx == part)
                                { fp = &A.done[((l - 1) * PARTS + idx) * FS]; tgt = t + 1; fm = f_fl_par; } }
                else          { if (t >= DRING && l < A.NL - 1 && idx == part)
                                { fp = &A.done[((l + 1) * PARTS + idx) * FS]; tgt = t - DRING + 1; fm = f_fl_child; } }
                if (fp) wait_flag(fp, tgt, fm);
            }
            __syncthreads();

            // ---- async stage issue (input t), then hh gemm covers the RTT ----
            vf4 s0, s1;
            const bool stg = (l > 0);
            if (stg) {
                const float* slot = A.rings + ((size_t)((l - 1) * PARTS + part) * DRING + (t & 3)) * 4096;
                if (f_in) ld_l2_2xf4_async(slot + 4 * tid, slot + 4 * (tid + TPB), s0, s1);
                else      ld_cp_2xf4_async(slot + 4 * tid, slot + 4 * (tid + TPB), s0, s1);
            }

            if (t > 0) gemmP(wt_hh, hbuf, 64, accR, accZ, accNH);

            if (stg) {
                vmwait0();
                *(vf4*)&atile[4 * tid] = s0;
                *(vf4*)&atile[4 * (tid + TPB)] = s1;
            }
            __syncthreads();

            // ---- ih: XG (l==0) or gemm from landed atile ----
            if (l == 0) {
                const float* xgp = A.xg + (size_t)t * XGT + 64 * part + b0;
                auto xgacc = [&](int row, float (&acc)[4]) {
                    float4 xv = *(const float4*)&xgp[(size_t)row * 128];
                    acc[0] += xv.x; acc[1] += xv.y; acc[2] += xv.z; acc[3] += xv.w;
                };
                xgacc(jl0, accR[0]);            xgacc(jl1, accR[1]);
                xgacc(JS + jl0, accZ[0]);       xgacc(JS + jl1, accZ[1]);
                xgacc(2 * JS + jl0, accNI[0]);  xgacc(2 * JS + jl1, accNI[1]);
            } else {
                gemmP(wt_ih, atile, 64, accR, accZ, accNI);
            }
        } else {
            // ---- STACK 2: all polls upfront (disjoint thread groups) ----
            if (t > 0 && tid < 4 && tid != part)
                wait_flag(&A.done[(l * 4 + tid) * FS], t, f_fl_self);
            if (tid >= 8 && tid < 16) {
                int grp = (tid - 8) >> 2, idx = tid & 3;
                int* fp = nullptr; int tgt = 0; bool fm = false;
                if (grp == 0) { if (l > 0) { fp = &A.done[((l - 1) * 4 + idx) * FS]; tgt = t + 1; fm = f_fl_par; } }
                else          { if (t >= DRING && l < A.NL - 1)
                                { fp = &A.done[((l + 1) * 4 + idx) * FS]; tgt = t - DRING + 1; fm = f_fl_child; } }
                if (fp) wait_flag(fp, tgt, fm);
            }
            __syncthreads();

            // ---- prefetch ih-kt0 (32KB) into regs; completes during hh ----
            vf4 e0, e1, e2, e3;
            const bool pih = (l > 0);
            if (pih) {
                const float* p[4];
#pragma unroll
                for (int q = 0; q < 4; ++q) p[q] = stage2_addr((l - 1) * 4, t & 3, 0, q);
                if (f_in) ld_l2_4xf4_async(p[0], p[1], p[2], p[3], e0, e1, e2, e3);
                else      ld_cp_4xf4_async(p[0], p[1], p[2], p[3], e0, e1, e2, e3);
            }

            // ---- hh from sibling rings (unchanged) ----
            if (t > 0) {
                for (int kt = 0; kt < 2; ++kt) {
                    if (kt) __syncthreads();
                    stage2(l * 4, (t - 1) & 3, kt, f_out);
                    __syncthreads();
                    gemmP(wt_hh + kt * 32 * WROW, atile, 128, accR, accZ, accNH);
                }
            }

            // ---- ih: XG (l==0) or landed-kt0 + staged-kt1 ----
            if (l == 0) {
                const float* xgp = A.xg + (size_t)t * XGT + b0;
                auto xgacc = [&](int row, float (&acc)[4]) {
                    float4 xv = *(const float4*)&xgp[(size_t)row * 128];
                    acc[0] += xv.x; acc[1] += xv.y; acc[2] += xv.z; acc[3] += xv.w;
                };
                xgacc(grow(jl0), accR[0]);            xgacc(grow(jl1), accR[1]);
                xgacc(grow(JS + jl0), accZ[0]);       xgacc(grow(JS + jl1), accZ[1]);
                xgacc(grow(2 * JS + jl0), accNI[0]);  xgacc(grow(2 * JS + jl1), accNI[1]);
            } else {
                __syncthreads();          // hh gemm done before atile overwrite
                vmwait0();                // prefetch long since complete
                stage2_land(e0, e1, e2, e3);
                __syncthreads();
                gemmP(wt_ih, atile, 128, accR, accZ, accNI);
                __syncthreads();
                stage2((l - 1) * 4, t & 3, 1, f_in);
                __syncthreads();
                gemmP(wt_ih + 32 * WROW, atile, 128, accR, accZ, accNI);
            }
        }

        // ---- gates + h update + publish ----
        float4 hv[2];
#pragma unroll
        for (int jj = 0; jj < 2; ++jj) {
            float* hp = (float*)&hv[jj];
#pragma unroll
            for (int bb = 0; bb < 4; ++bb) {
                float r = sigmoid_f(accR[jj][bb] + bR[jj]);
                float z = sigmoid_f(accZ[jj][bb] + bZ[jj]);
                float n = tanh_f(accNI[jj][bb] + bNI[jj] + r * (accNH[jj][bb] + bNH[jj]));
                float h = (1.0f - z) * n + z * hprev[jj][bb];
                hprev[jj][bb] = h;
                hp[bb] = h;
            }
        }
        float* slot = A.rings + ((size_t)rb * DRING + (t & 3)) * 4096;
        if (STACK == 2) {
            if (f_out) {
                st_l2_f4(&slot[jl0 * 128 + b0], hv[0]);
                st_l2_f4(&slot[jl1 * 128 + b0], hv[1]);
            } else {
                st_cp_f4(&slot[jl0 * 128 + b0], hv[0]);
                st_cp_f4(&slot[jl1 * 128 + b0], hv[1]);
            }
            if (A.seqOut && l == A.NL - 1) {
                *(float4*)&A.seqOut[(size_t)t * 16384 + (32 * part + jl0) * 128 + b0] = hv[0];
                *(float4*)&A.seqOut[(size_t)t * 16384 + (32 * part + jl1) * 128 + b0] = hv[1];
            }
        } else {
            if (f_out) {
                st_l2_f4(&slot[jl0 * 64 + b0], hv[0]);
                st_l2_f4(&slot[jl1 * 64 + b0], hv[1]);
            } else {
                st_cp_f4(&slot[jl0 * 64 + b0], hv[0]);
                st_cp_f4(&slot[jl1 * 64 + b0], hv[1]);
            }
            *(float4*)&hbuf[jl0 * 64 + b0] = hv[0];
            *(float4*)&hbuf[jl1 * 64 + b0] = hv[1];
            if (A.seqOut && l == A.NL - 1) {
                *(float4*)&A.seqOut[(size_t)t * 16384 + jl0 * 128 + 64 * part + b0] = hv[0];
                *(float4*)&A.seqOut[(size_t)t * 16384 + jl1 * 128 + 64 * part + b0] = hv[1];
            }
            if (STACK == 3 && l == A.NL - 1 && t == 95 && A.hFinal) {
                *(float4*)&A.hFinal[jl0 * 128 + 64 * part + b0] = hv[0];
                *(float4*)&A.hFinal[jl1 * 128 + 64 * part + b0] = hv[1];
            }
        }
        // drain sc0/sc1 stores + barrier, then flag publish (r9 protocol)
        vmwait0();
        __syncthreads();
        if (tid == 0) {
            if (f_fl_self) st_l2_b32(&A.done[rb * FS], t + 1);
            else           cp_store(&A.done[rb * FS], t + 1);
        }
    }
}

// XG[t][r][b] = sum_k W[r][k] * X[t][k][b]  (layer-0 ih gates, all t)
__global__ __launch_bounds__(256) void xg_kernel(const float* __restrict__ W,
    const float* __restrict__ X, float* __restrict__ XG,
    int NGtot, int din, long xts)
{
    __shared__ float xs[16384];
    const int t = blockIdx.x, r0 = blockIdx.y * 64, tid = threadIdx.x;
    for (int i = tid; i < din * 128; i += 256)
        xs[i] = X[(size_t)t * xts + i];
    __syncthreads();
    const int rr = tid >> 2, bq = tid & 3;
    const int r = r0 + rr;
    vf4 acc[8];
#pragma unroll
    for (int j = 0; j < 8; ++j) acc[j] = (vf4){0.f, 0.f, 0.f, 0.f};
    for (int k = 0; k < din; ++k) {
        float w = W[(size_t)r * din + k];
        const float* xr = &xs[k * 128 + bq * 32];
#pragma unroll
        for (int j = 0; j < 8; ++j) {
            vf4 xv = *(const vf4*)(xr + 4 * j);
            acc[j] += w * xv;
        }
    }
    float* out = &XG[((size_t)t * NGtot + r) * 128 + bq * 32];
#pragma unroll
    for (int j = 0; j < 8; ++j) *(vf4*)(out + 4 * j) = acc[j];
}

__global__ void xprep_kernel(const float* __restrict__ x, float* __restrict__ seqA)
{
    int i = blockIdx.x * 256 + threadIdx.x;
    if (i < 128 * 96 * 3) {
        int b = i / 288, r = i - b * 288;
        int t = r / 3, k = r - 3 * t;
        seqA[(size_t)t * 8192 + k * 128 + b] = x[i];
    }
}

__global__ __launch_bounds__(256) void head_kernel(
    const float* __restrict__ hF,
    const float* __restrict__ d1w, const float* __restrict__ d1b,
    const float* __restrict__ d2w, const float* __restrict__ d2b,
    const float* __restrict__ d3w, const float* __restrict__ d3b,
    float* __restrict__ out)
{
    const int b = blockIdx.x, tid = threadIdx.x;
    __shared__ float h1[64], h2[32];
    if (tid < 64) {
        float s = d1b[tid];
        for (int k = 0; k < 64; ++k) s += d1w[tid * 64 + k] * hF[k * 128 + b];
        h1[tid] = fmaxf(s, 0.0f);
    }
    __syncthreads();
    if (tid < 32) {
        float s = d2b[tid];
        for (int k = 0; k < 64; ++k) s += d2w[tid * 64 + k] * h1[k];
        h2[tid] = fmaxf(s, 0.0f);
    }
    __syncthreads();
    if (tid < 250) {
        float s = d3b[tid];
        for (int k = 0; k < 32; ++k) s += d3w[tid * 32 + k] * h2[k];
        out[b * 250 + tid] = fmaxf(s, 0.0f);
    }
}

extern "C" void kernel_launch(void* const* d_in, const int* in_sizes, int n_in,
                              void* d_out, int out_size, void* d_ws, size_t ws_size,
                              hipStream_t stream)
{
    const float* x       = (const float*)d_in[0];
    const float* g1_wih0 = (const float*)d_in[1];  const float* g1_bih0 = (const float*)d_in[2];
    const float* g1_whh0 = (const float*)d_in[3];  const float* g1_bhh0 = (const float*)d_in[4];
    const float* g1_wih  = (const float*)d_in[5];  const float* g1_bih  = (const float*)d_in[6];
    const float* g1_whh  = (const float*)d_in[7];  const float* g1_bhh  = (const float*)d_in[8];
    const float* g2_wih0 = (const float*)d_in[9];  const float* g2_bih0 = (const float*)d_in[10];
    const float* g2_whh0 = (const float*)d_in[11]; const float* g2_bhh0 = (const float*)d_in[12];
    const float* g2_wih  = (const float*)d_in[13]; const float* g2_bih  = (const float*)d_in[14];
    const float* g2_whh  = (const float*)d_in[15]; const float* g2_bhh  = (const float*)d_in[16];
    const float* g3_wih0 = (const float*)d_in[17]; const float* g3_bih0 = (const float*)d_in[18];
    const float* g3_whh0 = (const float*)d_in[19]; const float* g3_bhh0 = (const float*)d_in[20];
    const float* g3_wih  = (const float*)d_in[21]; const float* g3_bih  = (const float*)d_in[22];
    const float* g3_whh  = (const float*)d_in[23]; const float* g3_bhh  = (const float*)d_in[24];
    const float* d1w = (const float*)d_in[25]; const float* d1b = (const float*)d_in[26];
    const float* d2w = (const float*)d_in[27]; const float* d2b = (const float*)d_in[28];
    const float* d3w = (const float*)d_in[29]; const float* d3b = (const float*)d_in[30];

    float* wsf = (float*)d_ws;
    const size_t RINGS = (size_t)192 * DRING * 4096;
    const size_t B1SZ  = (size_t)96 * 128 * 128;
    const size_t SEQA  = (size_t)96 * 64 * 128;
    const int    SLOTN = 192 * FS;
    float* rings  = wsf;
    float* B1     = rings + RINGS;
    float* B2     = B1 + B1SZ;
    float* seqA   = B2 + B1SZ;
    float* hFinal = seqA + SEQA;
    int*   flags  = (int*)(hFinal + 8192);
    int*   prb    = flags + (size_t)4 * SLOTN;
    float* XG     = (float*)(prb + (size_t)4 * SLOTN);   // 96*384*128 floats (reused per pass)

    size_t zero_bytes = (B1SZ * 2 + SEQA + 8192) * sizeof(float)
                      + (size_t)8 * SLOTN * sizeof(int);
    (void)hipMemsetAsync(B1, 0, zero_bytes, stream);

    xprep_kernel<<<dim3(144), dim3(256), 0, stream>>>(x, seqA);

    PassArgs P;
    xg_kernel<<<dim3(96, 3), dim3(256), 0, stream>>>(g1_wih0, seqA, XG, 192, 3, 8192);
    P = {g1_wih0, g1_bih0, g1_whh0, g1_bhh0, g1_wih, g1_bih, g1_whh, g1_bhh,
         0, 96, seqA, 8192, B1, nullptr, rings, flags + 0 * SLOTN, prb + 0 * SLOTN, XG};
    pass_kernel<1><<<dim3(192), dim3(TPB), 0, stream>>>(P);

    xg_kernel<<<dim3(96, 6), dim3(256), 0, stream>>>(g2_wih0, B1, XG, 384, 64, 16384);
    P = {g2_wih0, g2_bih0, g2_whh0, g2_bhh0, g2_wih, g2_bih, g2_whh, g2_bhh,
         0, 48, B1, 16384, B2, nullptr, rings, flags + 1 * SLOTN, prb + 1 * SLOTN, XG};
    pass_kernel<2><<<dim3(192), dim3(TPB), 0, stream>>>(P);

    xg_kernel<<<dim3(96, 6), dim3(256), 0, stream>>>(g2_wih + (size_t)47 * 384 * 128, B2, XG,
                                                     384, 128, 16384);
    P = {g2_wih0, g2_bih0, g2_whh0, g2_bhh0, g2_wih, g2_bih, g2_whh, g2_bhh,
         48, 48, B2, 16384, B1, nullptr, rings, flags + 2 * SLOTN, prb + 2 * SLOTN, XG};
    pass_kernel<2><<<dim3(192), dim3(TPB), 0, stream>>>(P);

    xg_kernel<<<dim3(96, 3), dim3(256), 0, stream>>>(g3_wih0, B1, XG, 192, 128, 16384);
    P = {g3_wih0, g3_bih0, g3_whh0, g3_bhh0, g3_wih, g3_bih, g3_whh, g3_bhh,
         0, 96, B1, 16384, nullptr, hFinal, rings, flags + 3 * SLOTN, prb + 3 * SLOTN, XG};
    pass_kernel<3><<<dim3(192), dim3(TPB), 0, stream>>>(P);

    head_kernel<<<dim3(128), dim3(256), 0, stream>>>(hFinal, d1w, d1b, d2w, d2b, d3w, d3b,
                                                     (float*)d_out);
}

// Round 8
// 9176.229 us; speedup vs baseline: 1.2374x; 1.2374x over previous
//
#include <hip/hip_runtime.h>

// GRU_781684048417 — round 13: r11 (known-good 9.30ms) + LDS-broadcast remap.
//
// r12 post-mortem: poll-first ordering exposed the parent flag RTT that r11's
// hh-first ordering hid -> full revert to r11 structure.
//
// New lever: with gg = tid&31, EVERY wave contains all 32 gg values and
// re-reads the ENTIRE 48KB weight matrix from LDS per gemm (96 b128/wave
// x 1536B distinct each) -> ~5-8us/step of LDS bandwidth, the dominant
// non-VALU cost.  Remap gg = tid/BGN, bg = tid%BGN (BGN=16 stacks1/3, 32
// stack2): a wave now holds only 4 (resp 2) distinct gg -> weight b128s
// become 64-192B-distinct broadcasts (same-address reads are free, m136);
// the weight matrix is read once per CU per gemm instead of once per WAVE.
// Pure thread permutation: all downstream indices derive from (gg,bg).

#define TPB 512
#define DRING 4
#define FS 64                       // ints per flag/probe slot (256 B)
#define PROBE_A 0x51CAFE77
#define PROBE_B 0x2B2B2B2B

typedef float vf4 __attribute__((ext_vector_type(4)));

__device__ __forceinline__ float sigmoid_f(float x) { return 1.0f / (1.0f + __expf(-x)); }
__device__ __forceinline__ float tanh_f(float x)    { return 1.0f - 2.0f / (__expf(2.0f * x) + 1.0f); }

// ---- coherence-point flag ops: relaxed agent-scope atomics ----
__device__ __forceinline__ int cp_load(const int* p) {
    return __hip_atomic_load(p, __ATOMIC_RELAXED, __HIP_MEMORY_SCOPE_AGENT);
}
__device__ __forceinline__ void cp_store(int* p, int v) {
    __hip_atomic_store(p, v, __ATOMIC_RELAXED, __HIP_MEMORY_SCOPE_AGENT);
}
__device__ __forceinline__ int cp_poll_nz(const int* p) {
    int v;
    while (!(v = cp_load(p))) __builtin_amdgcn_s_sleep(8);
    return v;
}

// ---- intra-XCD (shared L2) ops: sc0 = bypass L1, service at XCD L2 ----
__device__ __forceinline__ void vmwait0() { asm volatile("s_waitcnt vmcnt(0)" ::: "memory"); }
__device__ __forceinline__ int ld_l2_b32_wait(const int* p) {
    int r;
    asm volatile("global_load_dword %0, %1, off sc0\n\t"
                 "s_waitcnt vmcnt(0)"
                 : "=v"(r) : "v"(p) : "memory");
    return r;
}
__device__ __forceinline__ void st_l2_b32(int* p, int v) {
    asm volatile("global_store_dword %0, %1, off sc0" :: "v"(p), "v"(v) : "memory");
}
__device__ __forceinline__ void st_l2_f4(float* p, float4 v) {
    vf4 w; w[0] = v.x; w[1] = v.y; w[2] = v.z; w[3] = v.w;
    asm volatile("global_store_dwordx4 %0, %1, off sc0" :: "v"(p), "v"(w) : "memory");
}
__device__ __forceinline__ void ld_l2_2xf4(const float* p0, const float* p1,
                                           vf4& a, vf4& b) {
    asm volatile("global_load_dwordx4 %0, %2, off sc0\n\t"
                 "global_load_dwordx4 %1, %3, off sc0\n\t"
                 "s_waitcnt vmcnt(0)"
                 : "=&v"(a), "=&v"(b)
                 : "v"(p0), "v"(p1)
                 : "memory");
}
__device__ __forceinline__ void ld_l2_4xf4(const float* p0, const float* p1,
                                           const float* p2, const float* p3,
                                           vf4& a, vf4& b, vf4& c, vf4& d) {
    asm volatile("global_load_dwordx4 %0, %4, off sc0\n\t"
                 "global_load_dwordx4 %1, %5, off sc0\n\t"
                 "global_load_dwordx4 %2, %6, off sc0\n\t"
                 "global_load_dwordx4 %3, %7, off sc0\n\t"
                 "s_waitcnt vmcnt(0)"
                 : "=&v"(a), "=&v"(b), "=&v"(c), "=&v"(d)
                 : "v"(p0), "v"(p1), "v"(p2), "v"(p3)
                 : "memory");
}

// ---- cross-XCD (coherence-point) wide ops: sc0 sc1 = bypass L1 AND L2 ----
__device__ __forceinline__ void st_cp_f4(float* p, float4 v) {
    vf4 w; w[0] = v.x; w[1] = v.y; w[2] = v.z; w[3] = v.w;
    asm volatile("global_store_dwordx4 %0, %1, off sc0 sc1" :: "v"(p), "v"(w) : "memory");
}
__device__ __forceinline__ void ld_cp_2xf4(const float* p0, const float* p1,
                                           vf4& a, vf4& b) {
    asm volatile("global_load_dwordx4 %0, %2, off sc0 sc1\n\t"
                 "global_load_dwordx4 %1, %3, off sc0 sc1\n\t"
                 "s_waitcnt vmcnt(0)"
                 : "=&v"(a), "=&v"(b)
                 : "v"(p0), "v"(p1)
                 : "memory");
}
__device__ __forceinline__ void ld_cp_4xf4(const float* p0, const float* p1,
                                           const float* p2, const float* p3,
                                           vf4& a, vf4& b, vf4& c, vf4& d) {
    asm volatile("global_load_dwordx4 %0, %4, off sc0 sc1\n\t"
                 "global_load_dwordx4 %1, %5, off sc0 sc1\n\t"
                 "global_load_dwordx4 %2, %6, off sc0 sc1\n\t"
                 "global_load_dwordx4 %3, %7, off sc0 sc1\n\t"
                 "s_waitcnt vmcnt(0)"
                 : "=&v"(a), "=&v"(b), "=&v"(c), "=&v"(d)
                 : "v"(p0), "v"(p1), "v"(p2), "v"(p3)
                 : "memory");
}

__device__ __forceinline__ void wait_flag(int* fp, int tgt, bool fast) {
    if (fast) { while (ld_l2_b32_wait(fp) < tgt) __builtin_amdgcn_s_sleep(1); }
    else      { while (cp_load(fp) < tgt)        __builtin_amdgcn_s_sleep(2); }
}

struct PassArgs {
    const float* wih0; const float* bih0; const float* whh0; const float* bhh0;
    const float* wihA; const float* bihA; const float* whhA; const float* bhhA;
    int firstLayer;
    int NL;
    const float* seqIn;
    long seqTs;
    float* seqOut;
    float* hFinal;
    float* rings;            // [192][DRING][4096]
    int* done;               // [192][FS]
    int* prb;                // [192][FS] probe slots
    const float* xg;         // [96][NGtot][128] precomputed layer-0 ih gates
};

template<int STACK>
__global__ __launch_bounds__(TPB, 2) void pass_kernel(PassArgs A)
{
    constexpr int NG    = (STACK == 2) ? 96 : 192;   // gate rows per block
    constexpr int NB    = (STACK == 2) ? 128 : 64;   // batch rows per block
    constexpr int KH    = (STACK == 2) ? 128 : 64;   // recurrent K
    constexpr int KI    = (STACK == 2) ? 128 : 64;   // input K (l>0)
    constexpr int PARTS = (STACK == 2) ? 4 : 2;
    constexpr int JS    = NG / 3;
    constexpr int NGG   = NG / 6;
    constexpr int BGN   = TPB / NGG;                 // batch groups (16 or 32)
    constexpr int WROW  = NGG * 12;                  // packed floats per k-pair
    constexpr int XGT   = (STACK == 2) ? 384 * 128 : 192 * 128;

    // packed weights: [k/2][gg][12] = R0 R1 Z0 Z1 N0 N1 (k) | same (k+1)
    __shared__ __align__(16) float wt_hh[(KH / 2) * WROW];
    __shared__ __align__(16) float wt_ih[(KI / 2) * WROW];
    __shared__ __align__(16) float atile[64 * NB];
    __shared__ __align__(16) float hbuf[64 * 64];

    const int tid  = threadIdx.x;

    // layer->blockIdx swizzle (XCD grouping heuristic; probes carry correctness)
    const int bidx = blockIdx.x;
    int l, part;
    if (STACK == 2) { l = 6  * (bidx & 7) + ((bidx >> 3) >> 2); part = (bidx >> 3) & 3; }
    else            { l = 12 * (bidx & 7) + ((bidx >> 3) >> 1); part = (bidx >> 3) & 1; }
    const int rb = l * PARTS + part;
    const int gl = A.firstLayer + l;

    // LDS-broadcast remap: a wave holds only TPB/(64*BGN)... few distinct gg
    // -> weight ds_read_b128 is mostly same-address broadcast.  Pure thread
    // permutation; all downstream indices derive from (gg, bg).
    const int gg = tid / BGN;
    const int bg = tid % BGN;
    const int jl0 = 2 * gg, jl1 = 2 * gg + 1;
    const int b0 = 4 * bg;

    const float *wih, *bih, *whh, *bhh;
    if (gl == 0) { wih = A.wih0; bih = A.bih0; whh = A.whh0; bhh = A.bhh0; }
    else {
        const int wsz = (STACK == 2) ? 384 * 128 : 192 * 64;
        const int bs  = (STACK == 2) ? 384 : 192;
        wih = A.wihA + (size_t)(gl - 1) * wsz; bih = A.bihA + (size_t)(gl - 1) * bs;
        whh = A.whhA + (size_t)(gl - 1) * wsz; bhh = A.bhhA + (size_t)(gl - 1) * bs;
    }

    auto grow = [&](int r) -> int {
        if (STACK == 2) return (r >> 5) * 128 + 32 * part + (r & 31);
        return r;
    };

    // ---- packed weight fills (wt_ih only for l>0; l==0 uses XG) ----
    for (int i = tid; i < NG * KH; i += TPB) {
        int r = i / KH, k = i - r * KH;
        int g = r / JS, j = r - g * JS;
        wt_hh[(k >> 1) * WROW + (j >> 1) * 12 + (k & 1) * 6 + g * 2 + (j & 1)]
            = whh[(size_t)grow(r) * KH + k];
    }
    if (l > 0) {
        for (int i = tid; i < NG * KI; i += TPB) {
            int r = i / KI, k = i - r * KI;
            int g = r / JS, j = r - g * JS;
            wt_ih[(k >> 1) * WROW + (j >> 1) * 12 + (k & 1) * 6 + g * 2 + (j & 1)]
                = wih[(size_t)grow(r) * KI + k];
        }
    }

    float bR[2], bZ[2], bNH[2], bNI[2];
#pragma unroll
    for (int jj = 0; jj < 2; ++jj) {
        int jl = jl0 + jj;
        bR[jj]  = bhh[grow(jl)]          + bih[grow(jl)];
        bZ[jj]  = bhh[grow(JS + jl)]     + bih[grow(JS + jl)];
        bNH[jj] = bhh[grow(2 * JS + jl)];
        bNI[jj] = bih[grow(2 * JS + jl)];
    }

    float hprev[2][4];
#pragma unroll
    for (int jj = 0; jj < 2; ++jj)
#pragma unroll
        for (int bb = 0; bb < 4; ++bb) hprev[jj][bb] = 0.0f;

    // ---------------- one-time L2-sharing probes + link modes ----------------
    bool f_in = false, f_out = false, f_fl_self = false, f_fl_par = false, f_fl_child = false;
    {
        int* hsk = (int*)atile;
        const int NL = A.NL;
        if (STACK != 2) {
            if (tid == 0 && l < NL - 1) {
                int* rg = A.prb + (size_t)rb * FS;
                cp_store(rg, PROBE_A); vmwait0();
                (void)ld_l2_b32_wait(rg);
                cp_store(rg, PROBE_B); vmwait0();
                cp_store(rg + 1, 1);
            }
            if (tid == 1 && l > 0) {
                int* rg = A.prb + (size_t)((l - 1) * PARTS + part) * FS;
                (void)cp_poll_nz(rg + 1);
                int v = ld_l2_b32_wait(rg);
                cp_store(rg + 2, (v == PROBE_A) ? 2 : 1);
            }
            if (tid >= 8 && tid < 12) {
                int j = l - 2 + (tid - 8);
                hsk[tid - 8] = (j >= 0 && j < NL - 1)
                    ? cp_poll_nz(A.prb + (size_t)(j * PARTS + part) * FS + 2) : 0;
            }
        } else {
            if (part == 0 && tid < 4 && (tid > 0 || l < NL - 1)) {
                int* rg = A.prb + (size_t)(l * 4 + tid) * FS;
                cp_store(rg, PROBE_A); vmwait0();
                (void)ld_l2_b32_wait(rg);
                cp_store(rg, PROBE_B); vmwait0();
                cp_store(rg + 1, 1);
            }
            if (tid == 4 && (part != 0 || l > 0)) {
                int* rg = (part != 0) ? A.prb + (size_t)(l * 4 + part) * FS
                                      : A.prb + (size_t)((l - 1) * 4) * FS;
                (void)cp_poll_nz(rg + 1);
                int v = ld_l2_b32_wait(rg);
                cp_store(rg + 2, (v == PROBE_A) ? 2 : 1);
            }
            if (tid >= 8 && tid < 28) {
                int q = tid - 8, r = q >> 2, p = q & 3;
                int a = l - 2 + r;
                bool valid = (a >= 0 && a < NL) && (p > 0 || a < NL - 1);
                hsk[q] = valid ? cp_poll_nz(A.prb + (size_t)(a * 4 + p) * FS + 2) : 0;
            }
        }
        __syncthreads();
        if (STACK != 2) {
            const int NLl = A.NL;
            bool pp0 = hsk[0] == 2, pp1 = hsk[1] == 2, pp2 = hsk[2] == 2, pp3 = hsk[3] == 2;
            f_in       = (l > 0) && pp1;
            f_out      = (l == NLl - 1) || pp2;
            f_fl_self  = (l == 0 || pp1) && (l == NLl - 1 || pp2);
            f_fl_par   = (l > 0) && pp1 && (l < 2 || pp0);
            f_fl_child = (l < NLl - 1) && pp2 && (l + 2 >= NLl || pp3);
        } else {
            const int NLl = A.NL;
            bool S[5], T[4];
#pragma unroll
            for (int r = 0; r < 5; ++r)
                S[r] = hsk[r * 4 + 1] == 2 && hsk[r * 4 + 2] == 2 && hsk[r * 4 + 3] == 2;
#pragma unroll
            for (int r = 0; r < 4; ++r) T[r] = hsk[r * 4 + 0] == 2;
            f_out      = S[2] && (l == NLl - 1 || (S[3] && T[2]));
            f_in       = (l > 0) && S[1] && S[2] && T[1];
            f_fl_self  = S[2] && (l == 0 || (S[1] && T[1])) && (l == NLl - 1 || (S[3] && T[2]));
            f_fl_par   = (l > 0) && S[1] && S[2] && T[1] && (l < 2 || (S[0] && T[0]));
            f_fl_child = (l < NLl - 1) && S[2] && S[3] && T[2] && (l + 2 >= NLl || (S[4] && T[3]));
        }
        __syncthreads();
    }

    // packed gemm: 32 k-pairs = 64 k per call.
    auto gemmP = [&](const float* wt, const float* at, int astride,
                     float (&accR)[2][4], float (&accZ)[2][4], float (&accN)[2][4]) {
#pragma unroll 2
        for (int k2 = 0; k2 < 32; ++k2) {
            const float* wr = wt + k2 * WROW + gg * 12;
            vf4 q0 = *(const vf4*)(wr);
            vf4 q1 = *(const vf4*)(wr + 4);
            vf4 q2 = *(const vf4*)(wr + 8);
            const float* ar = at + (2 * k2) * astride + b0;
            float4 a0v = *(const float4*)(ar);
            float4 a1v = *(const float4*)(ar + astride);
            float a0[4] = {a0v.x, a0v.y, a0v.z, a0v.w};
            float a1[4] = {a1v.x, a1v.y, a1v.z, a1v.w};
#pragma unroll
            for (int bb = 0; bb < 4; ++bb) {
                accR[0][bb] += q0.x * a0[bb];  accR[1][bb] += q0.y * a0[bb];
                accZ[0][bb] += q0.z * a0[bb];  accZ[1][bb] += q0.w * a0[bb];
                accN[0][bb] += q1.x * a0[bb];  accN[1][bb] += q1.y * a0[bb];
                accR[0][bb] += q1.z * a1[bb];  accR[1][bb] += q1.w * a1[bb];
                accZ[0][bb] += q2.x * a1[bb];  accZ[1][bb] += q2.y * a1[bb];
                accN[0][bb] += q2.z * a1[bb];  accN[1][bb] += q2.w * a1[bb];
            }
        }
    };

    // STACK2 ring staging (4096 floats per kt, 128-wide rows)
    auto stage2 = [&](int baseBlk, int slotT, int kt, bool fast) {
        const float* p[4];
#pragma unroll
        for (int q = 0; q < 4; ++q) {
            int u4 = tid + q * TPB, r = u4 >> 5, c4 = u4 & 31, kk = kt * 64 + r;
            p[q] = A.rings + ((size_t)(baseBlk + (kk >> 5)) * DRING + slotT) * 4096
                           + (kk & 31) * 128 + 4 * c4;
        }
        vf4 ta, tb, tc, td;
        if (fast) ld_l2_4xf4(p[0], p[1], p[2], p[3], ta, tb, tc, td);
        else      ld_cp_4xf4(p[0], p[1], p[2], p[3], ta, tb, tc, td);
        {
            int u4, r, c4;
            u4 = tid;           r = u4 >> 5; c4 = u4 & 31; *(vf4*)&atile[r * 128 + 4 * c4] = ta;
            u4 = tid + TPB;     r = u4 >> 5; c4 = u4 & 31; *(vf4*)&atile[r * 128 + 4 * c4] = tb;
            u4 = tid + 2 * TPB; r = u4 >> 5; c4 = u4 & 31; *(vf4*)&atile[r * 128 + 4 * c4] = tc;
            u4 = tid + 3 * TPB; r = u4 >> 5; c4 = u4 & 31; *(vf4*)&atile[r * 128 + 4 * c4] = td;
        }
    };

    for (int t = 0; t < 96; ++t) {
        float accR[2][4] = {}, accZ[2][4] = {}, accNH[2][4] = {}, accNI[2][4] = {};

        if (STACK != 2) {
            // ---- hh first (own LDS state; hides parent flag RTT) ----
            if (t > 0) gemmP(wt_hh, hbuf, 64, accR, accZ, accNH);

            // ---- parent(t) + child-antidep waits ----
            if (tid < 8) {
                int grp = tid >> 2, idx = tid & 3;
                int* fp = nullptr; int tgt = 0; bool fm = false;
                if (grp == 0) { if (l > 0 && idx == part)
                                { fp = &A.done[((l - 1) * PARTS + idx) * FS]; tgt = t + 1; fm = f_fl_par; } }
                else          { if (t >= DRING && l < A.NL - 1 && idx == part)
                                { fp = &A.done[((l + 1) * PARTS + idx) * FS]; tgt = t - DRING + 1; fm = f_fl_child; } }
                if (fp) wait_flag(fp, tgt, fm);
            }
            __syncthreads();

            // ---- ih: XG (l==0) or stage + gemm (l>0) ----
            if (l == 0) {
                const float* xgp = A.xg + (size_t)t * XGT + 64 * part + b0;
                auto xgacc = [&](int row, float (&acc)[4]) {
                    float4 xv = *(const float4*)&xgp[(size_t)row * 128];
                    acc[0] += xv.x; acc[1] += xv.y; acc[2] += xv.z; acc[3] += xv.w;
                };
                xgacc(jl0, accR[0]);            xgacc(jl1, accR[1]);
                xgacc(JS + jl0, accZ[0]);       xgacc(JS + jl1, accZ[1]);
                xgacc(2 * JS + jl0, accNI[0]);  xgacc(2 * JS + jl1, accNI[1]);
            } else {
                const float* slot = A.rings + ((size_t)((l - 1) * PARTS + part) * DRING + (t & 3)) * 4096;
                vf4 ta, tb;
                if (f_in) ld_l2_2xf4(slot + 4 * tid, slot + 4 * (tid + TPB), ta, tb);
                else      ld_cp_2xf4(slot + 4 * tid, slot + 4 * (tid + TPB), ta, tb);
                *(vf4*)&atile[4 * tid] = ta;
                *(vf4*)&atile[4 * (tid + TPB)] = tb;
                __syncthreads();
                gemmP(wt_ih, atile, 64, accR, accZ, accNI);
            }
        } else {
            // ---- STACK 2: sibling wait + hh from rings ----
            if (t > 0) {
                if (tid < 4 && tid != part)
                    wait_flag(&A.done[(l * 4 + tid) * FS], t, f_fl_self);
                __syncthreads();
                for (int kt = 0; kt < 2; ++kt) {
                    if (kt) __syncthreads();
                    stage2(l * 4, (t - 1) & 3, kt, f_out);
                    __syncthreads();
                    gemmP(wt_hh + kt * 32 * WROW, atile, 128, accR, accZ, accNH);
                }
            }

            // ---- parent + child waits ----
            if (tid < 8) {
                int grp = tid >> 2, idx = tid & 3;
                int* fp = nullptr; int tgt = 0; bool fm = false;
                if (grp == 0) { if (l > 0) { fp = &A.done[((l - 1) * 4 + idx) * FS]; tgt = t + 1; fm = f_fl_par; } }
                else          { if (t >= DRING && l < A.NL - 1)
                                { fp = &A.done[((l + 1) * 4 + idx) * FS]; tgt = t - DRING + 1; fm = f_fl_child; } }
                if (fp) wait_flag(fp, tgt, fm);
            }
            __syncthreads();

            // ---- ih: XG (l==0) or stage + gemm (l>0) ----
            if (l == 0) {
                const float* xgp = A.xg + (size_t)t * XGT + b0;
                auto xgacc = [&](int row, float (&acc)[4]) {
                    float4 xv = *(const float4*)&xgp[(size_t)row * 128];
                    acc[0] += xv.x; acc[1] += xv.y; acc[2] += xv.z; acc[3] += xv.w;
                };
                xgacc(grow(jl0), accR[0]);            xgacc(grow(jl1), accR[1]);
                xgacc(grow(JS + jl0), accZ[0]);       xgacc(grow(JS + jl1), accZ[1]);
                xgacc(grow(2 * JS + jl0), accNI[0]);  xgacc(grow(2 * JS + jl1), accNI[1]);
            } else {
                for (int kt = 0; kt < 2; ++kt) {
                    if (kt) __syncthreads();
                    stage2((l - 1) * 4, t & 3, kt, f_in);
                    __syncthreads();
                    gemmP(wt_ih + kt * 32 * WROW, atile, 128, accR, accZ, accNI);
                }
            }
        }

        // ---- gates + h update + publish ----
        float4 hv[2];
#pragma unroll
        for (int jj = 0; jj < 2; ++jj) {
            float* hp = (float*)&hv[jj];
#pragma unroll
            for (int bb = 0; bb < 4; ++bb) {
                float r = sigmoid_f(accR[jj][bb] + bR[jj]);
                float z = sigmoid_f(accZ[jj][bb] + bZ[jj]);
                float n = tanh_f(accNI[jj][bb] + bNI[jj] + r * (accNH[jj][bb] + bNH[jj]));
                float h = (1.0f - z) * n + z * hprev[jj][bb];
                hprev[jj][bb] = h;
                hp[bb] = h;
            }
        }
        float* slot = A.rings + ((size_t)rb * DRING + (t & 3)) * 4096;
        if (STACK == 2) {
            if (f_out) {
                st_l2_f4(&slot[jl0 * 128 + b0], hv[0]);
                st_l2_f4(&slot[jl1 * 128 + b0], hv[1]);
            } else {
                st_cp_f4(&slot[jl0 * 128 + b0], hv[0]);
                st_cp_f4(&slot[jl1 * 128 + b0], hv[1]);
            }
            if (A.seqOut && l == A.NL - 1) {
                *(float4*)&A.seqOut[(size_t)t * 16384 + (32 * part + jl0) * 128 + b0] = hv[0];
                *(float4*)&A.seqOut[(size_t)t * 16384 + (32 * part + jl1) * 128 + b0] = hv[1];
            }
        } else {
            if (f_out) {
                st_l2_f4(&slot[jl0 * 64 + b0], hv[0]);
                st_l2_f4(&slot[jl1 * 64 + b0], hv[1]);
            } else {
                st_cp_f4(&slot[jl0 * 64 + b0], hv[0]);
                st_cp_f4(&slot[jl1 * 64 + b0], hv[1]);
            }
            *(float4*)&hbuf[jl0 * 64 + b0] = hv[0];
            *(float4*)&hbuf[jl1 * 64 + b0] = hv[1];
            if (A.seqOut && l == A.NL - 1) {
                *(float4*)&A.seqOut[(size_t)t * 16384 + jl0 * 128 + 64 * part + b0] = hv[0];
                *(float4*)&A.seqOut[(size_t)t * 16384 + jl1 * 128 + 64 * part + b0] = hv[1];
            }
            if (STACK == 3 && l == A.NL - 1 && t == 95 && A.hFinal) {
                *(float4*)&A.hFinal[jl0 * 128 + 64 * part + b0] = hv[0];
                *(float4*)&A.hFinal[jl1 * 128 + 64 * part + b0] = hv[1];
            }
        }
        // drain sc0/sc1 stores + barrier, then flag publish (r9 protocol)
        vmwait0();
        __syncthreads();
        if (tid == 0) {
            if (f_fl_self) st_l2_b32(&A.done[rb * FS], t + 1);
            else           cp_store(&A.done[rb * FS], t + 1);
        }
    }
}

// XG[t][r][b] = sum_k W[r][k] * X[t][k][b]  (layer-0 ih gates, all t)
__global__ __launch_bounds__(256) void xg_kernel(const float* __restrict__ W,
    const float* __restrict__ X, float* __restrict__ XG,
    int NGtot, int din, long xts)
{
    __shared__ float xs[16384];
    const int t = blockIdx.x, r0 = blockIdx.y * 64, tid = threadIdx.x;
    for (int i = tid; i < din * 128; i += 256)
        xs[i] = X[(size_t)t * xts + i];
    __syncthreads();
    const int rr = tid >> 2, bq = tid & 3;
    const int r = r0 + rr;
    vf4 acc[8];
#pragma unroll
    for (int j = 0; j < 8; ++j) acc[j] = (vf4){0.f, 0.f, 0.f, 0.f};
    for (int k = 0; k < din; ++k) {
        float w = W[(size_t)r * din + k];
        const float* xr = &xs[k * 128 + bq * 32];
#pragma unroll
        for (int j = 0; j < 8; ++j) {
            vf4 xv = *(const vf4*)(xr + 4 * j);
            acc[j] += w * xv;
        }
    }
    float* out = &XG[((size_t)t * NGtot + r) * 128 + bq * 32];
#pragma unroll
    for (int j = 0; j < 8; ++j) *(vf4*)(out + 4 * j) = acc[j];
}

__global__ void xprep_kernel(const float* __restrict__ x, float* __restrict__ seqA)
{
    int i = blockIdx.x * 256 + threadIdx.x;
    if (i < 128 * 96 * 3) {
        int b = i / 288, r = i - b * 288;
        int t = r / 3, k = r - 3 * t;
        seqA[(size_t)t * 8192 + k * 128 + b] = x[i];
    }
}

__global__ __launch_bounds__(256) void head_kernel(
    const float* __restrict__ hF,
    const float* __restrict__ d1w, const float* __restrict__ d1b,
    const float* __restrict__ d2w, const float* __restrict__ d2b,
    const float* __restrict__ d3w, const float* __restrict__ d3b,
    float* __restrict__ out)
{
    const int b = blockIdx.x, tid = threadIdx.x;
    __shared__ float h1[64], h2[32];
    if (tid < 64) {
        float s = d1b[tid];
        for (int k = 0; k < 64; ++k) s += d1w[tid * 64 + k] * hF[k * 128 + b];
        h1[tid] = fmaxf(s, 0.0f);
    }
    __syncthreads();
    if (tid < 32) {
        float s = d2b[tid];
        for (int k = 0; k < 64; ++k) s += d2w[tid * 64 + k] * h1[k];
        h2[tid] = fmaxf(s, 0.0f);
    }
    __syncthreads();
    if (tid < 250) {
        float s = d3b[tid];
        for (int k = 0; k < 32; ++k) s += d3w[tid * 32 + k] * h2[k];
        out[b * 250 + tid] = fmaxf(s, 0.0f);
    }
}

extern "C" void kernel_launch(void* const* d_in, const int* in_sizes, int n_in,
                              void* d_out, int out_size, void* d_ws, size_t ws_size,
                              hipStream_t stream)
{
    const float* x       = (const float*)d_in[0];
    const float* g1_wih0 = (const float*)d_in[1];  const float* g1_bih0 = (const float*)d_in[2];
    const float* g1_whh0 = (const float*)d_in[3];  const float* g1_bhh0 = (const float*)d_in[4];
    const float* g1_wih  = (const float*)d_in[5];  const float* g1_bih  = (const float*)d_in[6];
    const float* g1_whh  = (const float*)d_in[7];  const float* g1_bhh  = (const float*)d_in[8];
    const float* g2_wih0 = (const float*)d_in[9];  const float* g2_bih0 = (const float*)d_in[10];
    const float* g2_whh0 = (const float*)d_in[11]; const float* g2_bhh0 = (const float*)d_in[12];
    const float* g2_wih  = (const float*)d_in[13]; const float* g2_bih  = (const float*)d_in[14];
    const float* g2_whh  = (const float*)d_in[15]; const float* g2_bhh  = (const float*)d_in[16];
    const float* g3_wih0 = (const float*)d_in[17]; const float* g3_bih0 = (const float*)d_in[18];
    const float* g3_whh0 = (const float*)d_in[19]; const float* g3_bhh0 = (const float*)d_in[20];
    const float* g3_wih  = (const float*)d_in[21]; const float* g3_bih  = (const float*)d_in[22];
    const float* g3_whh  = (const float*)d_in[23]; const float* g3_bhh  = (const float*)d_in[24];
    const float* d1w = (const float*)d_in[25]; const float* d1b = (const float*)d_in[26];
    const float* d2w = (const float*)d_in[27]; const float* d2b = (const float*)d_in[28];
    const float* d3w = (const float*)d_in[29]; const float* d3b = (const float*)d_in[30];

    float* wsf = (float*)d_ws;
    const size_t RINGS = (size_t)192 * DRING * 4096;
    const size_t B1SZ  = (size_t)96 * 128 * 128;
    const size_t SEQA  = (size_t)96 * 64 * 128;
    const int    SLOTN = 192 * FS;
    float* rings  = wsf;
    float* B1     = rings + RINGS;
    float* B2     = B1 + B1SZ;
    float* seqA   = B2 + B1SZ;
    float* hFinal = seqA + SEQA;
    int*   flags  = (int*)(hFinal + 8192);
    int*   prb    = flags + (size_t)4 * SLOTN;
    float* XG     = (float*)(prb + (size_t)4 * SLOTN);   // 96*384*128 floats (reused per pass)

    size_t zero_bytes = (B1SZ * 2 + SEQA + 8192) * sizeof(float)
                      + (size_t)8 * SLOTN * sizeof(int);
    (void)hipMemsetAsync(B1, 0, zero_bytes, stream);

    xprep_kernel<<<dim3(144), dim3(256), 0, stream>>>(x, seqA);

    PassArgs P;
    xg_kernel<<<dim3(96, 3), dim3(256), 0, stream>>>(g1_wih0, seqA, XG, 192, 3, 8192);
    P = {g1_wih0, g1_bih0, g1_whh0, g1_bhh0, g1_wih, g1_bih, g1_whh, g1_bhh,
         0, 96, seqA, 8192, B1, nullptr, rings, flags + 0 * SLOTN, prb + 0 * SLOTN, XG};
    pass_kernel<1><<<dim3(192), dim3(TPB), 0, stream>>>(P);

    xg_kernel<<<dim3(96, 6), dim3(256), 0, stream>>>(g2_wih0, B1, XG, 384, 64, 16384);
    P = {g2_wih0, g2_bih0, g2_whh0, g2_bhh0, g2_wih, g2_bih, g2_whh, g2_bhh,
         0, 48, B1, 16384, B2, nullptr, rings, flags + 1 * SLOTN, prb + 1 * SLOTN, XG};
    pass_kernel<2><<<dim3(192), dim3(TPB), 0, stream>>>(P);

    xg_kernel<<<dim3(96, 6), dim3(256), 0, stream>>>(g2_wih + (size_t)47 * 384 * 128, B2, XG,
                                                     384, 128, 16384);
    P = {g2_wih0, g2_bih0, g2_whh0, g2_bhh0, g2_wih, g2_bih, g2_whh, g2_bhh,
         48, 48, B2, 16384, B1, nullptr, rings, flags + 2 * SLOTN, prb + 2 * SLOTN, XG};
    pass_kernel<2><<<dim3(192), dim3(TPB), 0, stream>>>(P);

    xg_kernel<<<dim3(96, 3), dim3(256), 0, stream>>>(g3_wih0, B1, XG, 192, 128, 16384);
    P = {g3_wih0, g3_bih0, g3_whh0, g3_bhh0, g3_wih, g3_bih, g3_whh, g3_bhh,
         0, 96, B1, 16384, nullptr, hFinal, rings, flags + 3 * SLOTN, prb + 3 * SLOTN, XG};
    pass_kernel<3><<<dim3(192), dim3(TPB), 0, stream>>>(P);

    head_kernel<<<dim3(128), dim3(256), 0, stream>>>(hFinal, d1w, d1b, d2w, d2b, d3w, d3b,
                                                     (float*)d_out);
}

// Round 9
// 8108.321 us; speedup vs baseline: 1.4004x; 1.1317x over previous
//
#include <hip/hip_runtime.h>

// GRU_781684048417 — round 14: fuse passes 1-3 into one persistent kernel
// (overlap pipeline fill/drain across pass boundaries).
//
// r13 evidence: per-link p=15.6us with VALUBusy 37.7% == 5.9/15.6 -> every
// link adds a full step; passes 2/3 already at VALU floor (10.3us/step).
// Remaining big lever = fill/drain: each pass pays (NL-1) links of fill and
// the passes are stream-serialized.  This round: one kernel runs each
// block's pass1 -> pass2 -> pass3 roles back-to-back.  r13's swizzles
// compose: phase2 (l2,part4) from the same bidx == (l1/2, ...), order- and
// XCD-grouping-preserving.  Pass boundaries reuse the existing protocol:
// producer seqOut -> CP stores; consumer l==0 stages via CP loads gated on
// the previous pass's last-layer flags (XG reverts to a real gemm there).
// Rings: 3 private regions.  Pass 4 stays a separate dispatch (keeps XG;
// avoids the wideIH pacer).  Per-step protocol byte-identical to r13.

#define TPB 512
#define DRING 4
#define FS 64
#define PROBE_A 0x51CAFE77
#define PROBE_B 0x2B2B2B2B

typedef float vf4 __attribute__((ext_vector_type(4)));

__device__ __forceinline__ float sigmoid_f(float x) { return 1.0f / (1.0f + __expf(-x)); }
__device__ __forceinline__ float tanh_f(float x)    { return 1.0f - 2.0f / (__expf(2.0f * x) + 1.0f); }

__device__ __forceinline__ int cp_load(const int* p) {
    return __hip_atomic_load(p, __ATOMIC_RELAXED, __HIP_MEMORY_SCOPE_AGENT);
}
__device__ __forceinline__ void cp_store(int* p, int v) {
    __hip_atomic_store(p, v, __ATOMIC_RELAXED, __HIP_MEMORY_SCOPE_AGENT);
}
__device__ __forceinline__ int cp_poll_nz(const int* p) {
    int v;
    while (!(v = cp_load(p))) __builtin_amdgcn_s_sleep(8);
    return v;
}

__device__ __forceinline__ void vmwait0() { asm volatile("s_waitcnt vmcnt(0)" ::: "memory"); }
__device__ __forceinline__ int ld_l2_b32_wait(const int* p) {
    int r;
    asm volatile("global_load_dword %0, %1, off sc0\n\t"
                 "s_waitcnt vmcnt(0)"
                 : "=v"(r) : "v"(p) : "memory");
    return r;
}
__device__ __forceinline__ void st_l2_b32(int* p, int v) {
    asm volatile("global_store_dword %0, %1, off sc0" :: "v"(p), "v"(v) : "memory");
}
__device__ __forceinline__ void st_l2_f4(float* p, float4 v) {
    vf4 w; w[0] = v.x; w[1] = v.y; w[2] = v.z; w[3] = v.w;
    asm volatile("global_store_dwordx4 %0, %1, off sc0" :: "v"(p), "v"(w) : "memory");
}
__device__ __forceinline__ void ld_l2_2xf4(const float* p0, const float* p1,
                                           vf4& a, vf4& b) {
    asm volatile("global_load_dwordx4 %0, %2, off sc0\n\t"
                 "global_load_dwordx4 %1, %3, off sc0\n\t"
                 "s_waitcnt vmcnt(0)"
                 : "=&v"(a), "=&v"(b)
                 : "v"(p0), "v"(p1)
                 : "memory");
}
__device__ __forceinline__ void ld_l2_4xf4(const float* p0, const float* p1,
                                           const float* p2, const float* p3,
                                           vf4& a, vf4& b, vf4& c, vf4& d) {
    asm volatile("global_load_dwordx4 %0, %4, off sc0\n\t"
                 "global_load_dwordx4 %1, %5, off sc0\n\t"
                 "global_load_dwordx4 %2, %6, off sc0\n\t"
                 "global_load_dwordx4 %3, %7, off sc0\n\t"
                 "s_waitcnt vmcnt(0)"
                 : "=&v"(a), "=&v"(b), "=&v"(c), "=&v"(d)
                 : "v"(p0), "v"(p1), "v"(p2), "v"(p3)
                 : "memory");
}

__device__ __forceinline__ void st_cp_f4(float* p, float4 v) {
    vf4 w; w[0] = v.x; w[1] = v.y; w[2] = v.z; w[3] = v.w;
    asm volatile("global_store_dwordx4 %0, %1, off sc0 sc1" :: "v"(p), "v"(w) : "memory");
}
__device__ __forceinline__ void ld_cp_2xf4(const float* p0, const float* p1,
                                           vf4& a, vf4& b) {
    asm volatile("global_load_dwordx4 %0, %2, off sc0 sc1\n\t"
                 "global_load_dwordx4 %1, %3, off sc0 sc1\n\t"
                 "s_waitcnt vmcnt(0)"
                 : "=&v"(a), "=&v"(b)
                 : "v"(p0), "v"(p1)
                 : "memory");
}
__device__ __forceinline__ void ld_cp_4xf4(const float* p0, const float* p1,
                                           const float* p2, const float* p3,
                                           vf4& a, vf4& b, vf4& c, vf4& d) {
    asm volatile("global_load_dwordx4 %0, %4, off sc0 sc1\n\t"
                 "global_load_dwordx4 %1, %5, off sc0 sc1\n\t"
                 "global_load_dwordx4 %2, %6, off sc0 sc1\n\t"
                 "global_load_dwordx4 %3, %7, off sc0 sc1\n\t"
                 "s_waitcnt vmcnt(0)"
                 : "=&v"(a), "=&v"(b), "=&v"(c), "=&v"(d)
                 : "v"(p0), "v"(p1), "v"(p2), "v"(p3)
                 : "memory");
}

__device__ __forceinline__ void wait_flag(int* fp, int tgt, bool fast) {
    if (fast) { while (ld_l2_b32_wait(fp) < tgt) __builtin_amdgcn_s_sleep(1); }
    else      { while (cp_load(fp) < tgt)        __builtin_amdgcn_s_sleep(2); }
}

struct PassArgs {
    const float* wih0; const float* bih0; const float* whh0; const float* bhh0;
    const float* wihA; const float* bihA; const float* whhA; const float* bhhA;
    int firstLayer;
    int NL;
    const float* seqIn;
    long seqTs;
    float* seqOut;
    float* hFinal;
    float* rings;            // [192][DRING][4096]
    int* done;               // [192][FS]
    int* prb;                // [192][FS]
    const float* xg;         // non-null => l==0 uses precomputed ih gates
    const int* prevDone;     // non-null => in-kernel boundary for l==0
    int prevBase;            // flag index base of prev pass last layer
    int prevN;               // number of prev-part flags
    int cpSeqOut;            // 1 => seqOut via CP stores (in-kernel consumer)
};

template<int STACK>
__device__ void pass_body(const PassArgs& A, int l, int part, int tid,
                          float* wt_hh, float* wt_ih, float* atile, float* hbuf)
{
    constexpr int NG    = (STACK == 2) ? 96 : 192;
    constexpr int KH    = (STACK == 2) ? 128 : 64;
    constexpr int KI    = (STACK == 2) ? 128 : 64;
    constexpr int PARTS = (STACK == 2) ? 4 : 2;
    constexpr int JS    = NG / 3;
    constexpr int NGG   = NG / 6;
    constexpr int BGN   = TPB / NGG;
    constexpr int WROW  = NGG * 12;
    constexpr int XGT   = (STACK == 2) ? 384 * 128 : 192 * 128;

    const int rb = l * PARTS + part;
    const int gl = A.firstLayer + l;
    const bool useXG = (A.xg != nullptr);

    const int gg = tid / BGN;
    const int bg = tid % BGN;
    const int jl0 = 2 * gg, jl1 = 2 * gg + 1;
    const int b0 = 4 * bg;

    const float *wih, *bih, *whh, *bhh;
    if (gl == 0) { wih = A.wih0; bih = A.bih0; whh = A.whh0; bhh = A.bhh0; }
    else {
        const int wsz = (STACK == 2) ? 384 * 128 : 192 * 64;
        const int bs  = (STACK == 2) ? 384 : 192;
        wih = A.wihA + (size_t)(gl - 1) * wsz; bih = A.bihA + (size_t)(gl - 1) * bs;
        whh = A.whhA + (size_t)(gl - 1) * wsz; bhh = A.bhhA + (size_t)(gl - 1) * bs;
    }
    const int din = (gl == 0) ? ((STACK == 1) ? 3 : ((STACK == 2) ? 64 : 128))
                              : ((STACK == 2) ? 128 : 64);

    auto grow = [&](int r) -> int {
        if (STACK == 2) return (r >> 5) * 128 + 32 * part + (r & 31);
        return r;
    };

    for (int i = tid; i < NG * KH; i += TPB) {
        int r = i / KH, k = i - r * KH;
        int g = r / JS, j = r - g * JS;
        wt_hh[(k >> 1) * WROW + (j >> 1) * 12 + (k & 1) * 6 + g * 2 + (j & 1)]
            = whh[(size_t)grow(r) * KH + k];
    }
    if (l > 0 || !useXG) {
        for (int i = tid; i < NG * KI; i += TPB) {
            int r = i / KI, k = i - r * KI;
            int g = r / JS, j = r - g * JS;
            wt_ih[(k >> 1) * WROW + (j >> 1) * 12 + (k & 1) * 6 + g * 2 + (j & 1)]
                = (k < din) ? wih[(size_t)grow(r) * din + k] : 0.0f;
        }
    }

    float bR[2], bZ[2], bNH[2], bNI[2];
#pragma unroll
    for (int jj = 0; jj < 2; ++jj) {
        int jl = jl0 + jj;
        bR[jj]  = bhh[grow(jl)]          + bih[grow(jl)];
        bZ[jj]  = bhh[grow(JS + jl)]     + bih[grow(JS + jl)];
        bNH[jj] = bhh[grow(2 * JS + jl)];
        bNI[jj] = bih[grow(2 * JS + jl)];
    }

    float hprev[2][4];
#pragma unroll
    for (int jj = 0; jj < 2; ++jj)
#pragma unroll
        for (int bb = 0; bb < 4; ++bb) hprev[jj][bb] = 0.0f;

    // ---------------- probes + link modes (r13 protocol) ----------------
    bool f_in = false, f_out = false, f_fl_self = false, f_fl_par = false, f_fl_child = false;
    {
        int* hsk = (int*)atile;
        const int NL = A.NL;
        if (STACK != 2) {
            if (tid == 0 && l < NL - 1) {
                int* rg = A.prb + (size_t)rb * FS;
                cp_store(rg, PROBE_A); vmwait0();
                (void)ld_l2_b32_wait(rg);
                cp_store(rg, PROBE_B); vmwait0();
                cp_store(rg + 1, 1);
            }
            if (tid == 1 && l > 0) {
                int* rg = A.prb + (size_t)((l - 1) * PARTS + part) * FS;
                (void)cp_poll_nz(rg + 1);
                int v = ld_l2_b32_wait(rg);
                cp_store(rg + 2, (v == PROBE_A) ? 2 : 1);
            }
            if (tid >= 8 && tid < 12) {
                int j = l - 2 + (tid - 8);
                hsk[tid - 8] = (j >= 0 && j < NL - 1)
                    ? cp_poll_nz(A.prb + (size_t)(j * PARTS + part) * FS + 2) : 0;
            }
        } else {
            if (part == 0 && tid < 4 && (tid > 0 || l < NL - 1)) {
                int* rg = A.prb + (size_t)(l * 4 + tid) * FS;
                cp_store(rg, PROBE_A); vmwait0();
                (void)ld_l2_b32_wait(rg);
                cp_store(rg, PROBE_B); vmwait0();
                cp_store(rg + 1, 1);
            }
            if (tid == 4 && (part != 0 || l > 0)) {
                int* rg = (part != 0) ? A.prb + (size_t)(l * 4 + part) * FS
                                      : A.prb + (size_t)((l - 1) * 4) * FS;
                (void)cp_poll_nz(rg + 1);
                int v = ld_l2_b32_wait(rg);
                cp_store(rg + 2, (v == PROBE_A) ? 2 : 1);
            }
            if (tid >= 8 && tid < 28) {
                int q = tid - 8, r = q >> 2, p = q & 3;
                int a = l - 2 + r;
                bool valid = (a >= 0 && a < NL) && (p > 0 || a < NL - 1);
                hsk[q] = valid ? cp_poll_nz(A.prb + (size_t)(a * 4 + p) * FS + 2) : 0;
            }
        }
        __syncthreads();
        if (STACK != 2) {
            const int NLl = A.NL;
            bool pp0 = hsk[0] == 2, pp1 = hsk[1] == 2, pp2 = hsk[2] == 2, pp3 = hsk[3] == 2;
            f_in       = (l > 0) && pp1;
            f_out      = (l == NLl - 1) || pp2;
            f_fl_self  = (l == 0 || pp1) && (l == NLl - 1 || pp2);
            f_fl_par   = (l > 0) && pp1 && (l < 2 || pp0);
            f_fl_child = (l < NLl - 1) && pp2 && (l + 2 >= NLl || pp3);
        } else {
            const int NLl = A.NL;
            bool S[5], T[4];
#pragma unroll
            for (int r = 0; r < 5; ++r)
                S[r] = hsk[r * 4 + 1] == 2 && hsk[r * 4 + 2] == 2 && hsk[r * 4 + 3] == 2;
#pragma unroll
            for (int r = 0; r < 4; ++r) T[r] = hsk[r * 4 + 0] == 2;
            f_out      = S[2] && (l == NLl - 1 || (S[3] && T[2]));
            f_in       = (l > 0) && S[1] && S[2] && T[1];
            f_fl_self  = S[2] && (l == 0 || (S[1] && T[1])) && (l == NLl - 1 || (S[3] && T[2]));
            f_fl_par   = (l > 0) && S[1] && S[2] && T[1] && (l < 2 || (S[0] && T[0]));
            f_fl_child = (l < NLl - 1) && S[2] && S[3] && T[2] && (l + 2 >= NLl || (S[4] && T[3]));
        }
        __syncthreads();
    }

    auto gemmP = [&](const float* wt, const float* at, int astride,
                     float (&accR)[2][4], float (&accZ)[2][4], float (&accN)[2][4]) {
#pragma unroll 2
        for (int k2 = 0; k2 < 32; ++k2) {
            const float* wr = wt + k2 * WROW + gg * 12;
            vf4 q0 = *(const vf4*)(wr);
            vf4 q1 = *(const vf4*)(wr + 4);
            vf4 q2 = *(const vf4*)(wr + 8);
            const float* ar = at + (2 * k2) * astride + b0;
            float4 a0v = *(const float4*)(ar);
            float4 a1v = *(const float4*)(ar + astride);
            float a0[4] = {a0v.x, a0v.y, a0v.z, a0v.w};
            float a1[4] = {a1v.x, a1v.y, a1v.z, a1v.w};
#pragma unroll
            for (int bb = 0; bb < 4; ++bb) {
                accR[0][bb] += q0.x * a0[bb];  accR[1][bb] += q0.y * a0[bb];
                accZ[0][bb] += q0.z * a0[bb];  accZ[1][bb] += q0.w * a0[bb];
                accN[0][bb] += q1.x * a0[bb];  accN[1][bb] += q1.y * a0[bb];
                accR[0][bb] += q1.z * a1[bb];  accR[1][bb] += q1.w * a1[bb];
                accZ[0][bb] += q2.x * a1[bb];  accZ[1][bb] += q2.y * a1[bb];
                accN[0][bb] += q2.z * a1[bb];  accN[1][bb] += q2.w * a1[bb];
            }
        }
    };

    auto stage2 = [&](int baseBlk, int slotT, int kt, bool fast) {
        const float* p[4];
#pragma unroll
        for (int q = 0; q < 4; ++q) {
            int u4 = tid + q * TPB, r = u4 >> 5, c4 = u4 & 31, kk = kt * 64 + r;
            p[q] = A.rings + ((size_t)(baseBlk + (kk >> 5)) * DRING + slotT) * 4096
                           + (kk & 31) * 128 + 4 * c4;
        }
        vf4 ta, tb, tc, td;
        if (fast) ld_l2_4xf4(p[0], p[1], p[2], p[3], ta, tb, tc, td);
        else      ld_cp_4xf4(p[0], p[1], p[2], p[3], ta, tb, tc, td);
        {
            int u4, r, c4;
            u4 = tid;           r = u4 >> 5; c4 = u4 & 31; *(vf4*)&atile[r * 128 + 4 * c4] = ta;
            u4 = tid + TPB;     r = u4 >> 5; c4 = u4 & 31; *(vf4*)&atile[r * 128 + 4 * c4] = tb;
            u4 = tid + 2 * TPB; r = u4 >> 5; c4 = u4 & 31; *(vf4*)&atile[r * 128 + 4 * c4] = tc;
            u4 = tid + 3 * TPB; r = u4 >> 5; c4 = u4 & 31; *(vf4*)&atile[r * 128 + 4 * c4] = td;
        }
    };

    for (int t = 0; t < 96; ++t) {
        float accR[2][4] = {}, accZ[2][4] = {}, accNH[2][4] = {}, accNI[2][4] = {};

        if (STACK != 2) {
            if (t > 0) gemmP(wt_hh, hbuf, 64, accR, accZ, accNH);

            if (tid < 8) {
                int grp = tid >> 2, idx = tid & 3;
                int* fp = nullptr; int tgt = 0; bool fm = false;
                if (grp == 0) { if (l > 0 && idx == part)
                                { fp = &A.done[((l - 1) * PARTS + idx) * FS]; tgt = t + 1; fm = f_fl_par; } }
                else          { if (t >= DRING && l < A.NL - 1 && idx == part)
                                { fp = &A.done[((l + 1) * PARTS + idx) * FS]; tgt = t - DRING + 1; fm = f_fl_child; } }
                if (fp) wait_flag(fp, tgt, fm);
            }
            __syncthreads();

            if (l == 0) {
                const float* xgp = A.xg + (size_t)t * XGT + 64 * part + b0;
                auto xgacc = [&](int row, float (&acc)[4]) {
                    float4 xv = *(const float4*)&xgp[(size_t)row * 128];
                    acc[0] += xv.x; acc[1] += xv.y; acc[2] += xv.z; acc[3] += xv.w;
                };
                xgacc(jl0, accR[0]);            xgacc(jl1, accR[1]);
                xgacc(JS + jl0, accZ[0]);       xgacc(JS + jl1, accZ[1]);
                xgacc(2 * JS + jl0, accNI[0]);  xgacc(2 * JS + jl1, accNI[1]);
            } else {
                const float* slot = A.rings + ((size_t)((l - 1) * PARTS + part) * DRING + (t & 3)) * 4096;
                vf4 ta, tb;
                if (f_in) ld_l2_2xf4(slot + 4 * tid, slot + 4 * (tid + TPB), ta, tb);
                else      ld_cp_2xf4(slot + 4 * tid, slot + 4 * (tid + TPB), ta, tb);
                *(vf4*)&atile[4 * tid] = ta;
                *(vf4*)&atile[4 * (tid + TPB)] = tb;
                __syncthreads();
                gemmP(wt_ih, atile, 64, accR, accZ, accNI);
            }
        } else {
            if (t > 0) {
                if (tid < 4 && tid != part)
                    wait_flag(&A.done[(l * 4 + tid) * FS], t, f_fl_self);
                __syncthreads();
                for (int kt = 0; kt < 2; ++kt) {
                    if (kt) __syncthreads();
                    stage2(l * 4, (t - 1) & 3, kt, f_out);
                    __syncthreads();
                    gemmP(wt_hh + kt * 32 * WROW, atile, 128, accR, accZ, accNH);
                }
            }

            if (tid < 8) {
                int grp = tid >> 2, idx = tid & 3;
                int* fp = nullptr; int tgt = 0; bool fm = false;
                if (grp == 0) {
                    if (l > 0) { fp = &A.done[((l - 1) * 4 + idx) * FS]; tgt = t + 1; fm = f_fl_par; }
                    else if (A.prevDone && idx < A.prevN)
                         { fp = (int*)&A.prevDone[(A.prevBase + idx) * FS]; tgt = t + 1; fm = false; }
                }
                else { if (t >= DRING && l < A.NL - 1)
                       { fp = &A.done[((l + 1) * 4 + idx) * FS]; tgt = t - DRING + 1; fm = f_fl_child; } }
                if (fp) wait_flag(fp, tgt, fm);
            }
            __syncthreads();

            if (l == 0 && useXG) {
                const float* xgp = A.xg + (size_t)t * XGT + b0;
                auto xgacc = [&](int row, float (&acc)[4]) {
                    float4 xv = *(const float4*)&xgp[(size_t)row * 128];
                    acc[0] += xv.x; acc[1] += xv.y; acc[2] += xv.z; acc[3] += xv.w;
                };
                xgacc(grow(jl0), accR[0]);            xgacc(grow(jl1), accR[1]);
                xgacc(grow(JS + jl0), accZ[0]);       xgacc(grow(JS + jl1), accZ[1]);
                xgacc(grow(2 * JS + jl0), accNI[0]);  xgacc(grow(2 * JS + jl1), accNI[1]);
            } else {
                const int nkt = (l == 0 && A.firstLayer == 0) ? 1 : 2;
                for (int kt = 0; kt < nkt; ++kt) {
                    if (kt) __syncthreads();
                    if (l == 0) {
                        const float* src = A.seqIn + (size_t)t * A.seqTs + (size_t)kt * 64 * 128;
                        if (A.prevDone) {
                            vf4 a, b, c, d;
                            ld_cp_4xf4(src + 4 * tid, src + 4 * (tid + TPB),
                                       src + 4 * (tid + 2 * TPB), src + 4 * (tid + 3 * TPB),
                                       a, b, c, d);
                            *(vf4*)&atile[4 * tid] = a;
                            *(vf4*)&atile[4 * (tid + TPB)] = b;
                            *(vf4*)&atile[4 * (tid + 2 * TPB)] = c;
                            *(vf4*)&atile[4 * (tid + 3 * TPB)] = d;
                        } else {
                            for (int i = tid; i < 2048; i += TPB)
                                *(float4*)&atile[4 * i] = *(const float4*)(src + 4 * i);
                        }
                    } else {
                        stage2((l - 1) * 4, t & 3, kt, f_in);
                    }
                    __syncthreads();
                    gemmP(wt_ih + kt * 32 * WROW, atile, 128, accR, accZ, accNI);
                }
            }
        }

        // ---- gates + h update + publish ----
        float4 hv[2];
#pragma unroll
        for (int jj = 0; jj < 2; ++jj) {
            float* hp = (float*)&hv[jj];
#pragma unroll
            for (int bb = 0; bb < 4; ++bb) {
                float r = sigmoid_f(accR[jj][bb] + bR[jj]);
                float z = sigmoid_f(accZ[jj][bb] + bZ[jj]);
                float n = tanh_f(accNI[jj][bb] + bNI[jj] + r * (accNH[jj][bb] + bNH[jj]));
                float h = (1.0f - z) * n + z * hprev[jj][bb];
                hprev[jj][bb] = h;
                hp[bb] = h;
            }
        }
        float* slot = A.rings + ((size_t)rb * DRING + (t & 3)) * 4096;
        if (STACK == 2) {
            if (f_out) {
                st_l2_f4(&slot[jl0 * 128 + b0], hv[0]);
                st_l2_f4(&slot[jl1 * 128 + b0], hv[1]);
            } else {
                st_cp_f4(&slot[jl0 * 128 + b0], hv[0]);
                st_cp_f4(&slot[jl1 * 128 + b0], hv[1]);
            }
            if (A.seqOut && l == A.NL - 1) {
                float* o0 = &A.seqOut[(size_t)t * 16384 + (32 * part + jl0) * 128 + b0];
                float* o1 = &A.seqOut[(size_t)t * 16384 + (32 * part + jl1) * 128 + b0];
                if (A.cpSeqOut) { st_cp_f4(o0, hv[0]); st_cp_f4(o1, hv[1]); }
                else            { *(float4*)o0 = hv[0]; *(float4*)o1 = hv[1]; }
            }
        } else {
            if (f_out) {
                st_l2_f4(&slot[jl0 * 64 + b0], hv[0]);
                st_l2_f4(&slot[jl1 * 64 + b0], hv[1]);
            } else {
                st_cp_f4(&slot[jl0 * 64 + b0], hv[0]);
                st_cp_f4(&slot[jl1 * 64 + b0], hv[1]);
            }
            *(float4*)&hbuf[jl0 * 64 + b0] = hv[0];
            *(float4*)&hbuf[jl1 * 64 + b0] = hv[1];
            if (A.seqOut && l == A.NL - 1) {
                float* o0 = &A.seqOut[(size_t)t * 16384 + jl0 * 128 + 64 * part + b0];
                float* o1 = &A.seqOut[(size_t)t * 16384 + jl1 * 128 + 64 * part + b0];
                if (A.cpSeqOut) { st_cp_f4(o0, hv[0]); st_cp_f4(o1, hv[1]); }
                else            { *(float4*)o0 = hv[0]; *(float4*)o1 = hv[1]; }
            }
            if (STACK == 3 && l == A.NL - 1 && t == 95 && A.hFinal) {
                *(float4*)&A.hFinal[jl0 * 128 + 64 * part + b0] = hv[0];
                *(float4*)&A.hFinal[jl1 * 128 + 64 * part + b0] = hv[1];
            }
        }
        vmwait0();
        __syncthreads();
        if (tid == 0) {
            if (f_fl_self) st_l2_b32(&A.done[rb * FS], t + 1);
            else           cp_store(&A.done[rb * FS], t + 1);
        }
    }
}

// Fused passes 1-3: each block runs its pass1 role, then pass2, then pass3.
__global__ __launch_bounds__(TPB, 2) void fused_kernel(PassArgs P1, PassArgs P2, PassArgs P3)
{
    __shared__ __align__(16) float wt_hh[12288];
    __shared__ __align__(16) float wt_ih[12288];
    __shared__ __align__(16) float atile[8192];
    __shared__ __align__(16) float hbuf[4096];

    const int tid  = threadIdx.x;
    const int bidx = blockIdx.x;

    {
        int l = 12 * (bidx & 7) + ((bidx >> 3) >> 1), part = (bidx >> 3) & 1;
        pass_body<1>(P1, l, part, tid, wt_hh, wt_ih, atile, hbuf);
    }
    __syncthreads();
    {
        int l = 6 * (bidx & 7) + ((bidx >> 3) >> 2), part = (bidx >> 3) & 3;
        pass_body<2>(P2, l, part, tid, wt_hh, wt_ih, atile, hbuf);
        __syncthreads();
        pass_body<2>(P3, l, part, tid, wt_hh, wt_ih, atile, hbuf);
    }
}

__global__ __launch_bounds__(TPB, 2) void pass4_kernel(PassArgs A)
{
    __shared__ __align__(16) float wt_hh[12288];
    __shared__ __align__(16) float wt_ih[12288];
    __shared__ __align__(16) float atile[4096];
    __shared__ __align__(16) float hbuf[4096];

    const int tid  = threadIdx.x;
    const int bidx = blockIdx.x;
    int l = 12 * (bidx & 7) + ((bidx >> 3) >> 1), part = (bidx >> 3) & 1;
    pass_body<3>(A, l, part, tid, wt_hh, wt_ih, atile, hbuf);
}

// XG[t][r][b] = sum_k W[r][k] * X[t][k][b]
__global__ __launch_bounds__(256) void xg_kernel(const float* __restrict__ W,
    const float* __restrict__ X, float* __restrict__ XG,
    int NGtot, int din, long xts)
{
    __shared__ float xs[16384];
    const int t = blockIdx.x, r0 = blockIdx.y * 64, tid = threadIdx.x;
    for (int i = tid; i < din * 128; i += 256)
        xs[i] = X[(size_t)t * xts + i];
    __syncthreads();
    const int rr = tid >> 2, bq = tid & 3;
    const int r = r0 + rr;
    vf4 acc[8];
#pragma unroll
    for (int j = 0; j < 8; ++j) acc[j] = (vf4){0.f, 0.f, 0.f, 0.f};
    for (int k = 0; k < din; ++k) {
        float w = W[(size_t)r * din + k];
        const float* xr = &xs[k * 128 + bq * 32];
#pragma unroll
        for (int j = 0; j < 8; ++j) {
            vf4 xv = *(const vf4*)(xr + 4 * j);
            acc[j] += w * xv;
        }
    }
    float* out = &XG[((size_t)t * NGtot + r) * 128 + bq * 32];
#pragma unroll
    for (int j = 0; j < 8; ++j) *(vf4*)(out + 4 * j) = acc[j];
}

__global__ void xprep_kernel(const float* __restrict__ x, float* __restrict__ seqA)
{
    int i = blockIdx.x * 256 + threadIdx.x;
    if (i < 128 * 96 * 3) {
        int b = i / 288, r = i - b * 288;
        int t = r / 3, k = r - 3 * t;
        seqA[(size_t)t * 8192 + k * 128 + b] = x[i];
    }
}

__global__ __launch_bounds__(256) void head_kernel(
    const float* __restrict__ hF,
    const float* __restrict__ d1w, const float* __restrict__ d1b,
    const float* __restrict__ d2w, const float* __restrict__ d2b,
    const float* __restrict__ d3w, const float* __restrict__ d3b,
    float* __restrict__ out)
{
    const int b = blockIdx.x, tid = threadIdx.x;
    __shared__ float h1[64], h2[32];
    if (tid < 64) {
        float s = d1b[tid];
        for (int k = 0; k < 64; ++k) s += d1w[tid * 64 + k] * hF[k * 128 + b];
        h1[tid] = fmaxf(s, 0.0f);
    }
    __syncthreads();
    if (tid < 32) {
        float s = d2b[tid];
        for (int k = 0; k < 64; ++k) s += d2w[tid * 64 + k] * h1[k];
        h2[tid] = fmaxf(s, 0.0f);
    }
    __syncthreads();
    if (tid < 250) {
        float s = d3b[tid];
        for (int k = 0; k < 32; ++k) s += d3w[tid * 32 + k] * h2[k];
        out[b * 250 + tid] = fmaxf(s, 0.0f);
    }
}

extern "C" void kernel_launch(void* const* d_in, const int* in_sizes, int n_in,
                              void* d_out, int out_size, void* d_ws, size_t ws_size,
                              hipStream_t stream)
{
    const float* x       = (const float*)d_in[0];
    const float* g1_wih0 = (const float*)d_in[1];  const float* g1_bih0 = (const float*)d_in[2];
    const float* g1_whh0 = (const float*)d_in[3];  const float* g1_bhh0 = (const float*)d_in[4];
    const float* g1_wih  = (const float*)d_in[5];  const float* g1_bih  = (const float*)d_in[6];
    const float* g1_whh  = (const float*)d_in[7];  const float* g1_bhh  = (const float*)d_in[8];
    const float* g2_wih0 = (const float*)d_in[9];  const float* g2_bih0 = (const float*)d_in[10];
    const float* g2_whh0 = (const float*)d_in[11]; const float* g2_bhh0 = (const float*)d_in[12];
    const float* g2_wih  = (const float*)d_in[13]; const float* g2_bih  = (const float*)d_in[14];
    const float* g2_whh  = (const float*)d_in[15]; const float* g2_bhh  = (const float*)d_in[16];
    const float* g3_wih0 = (const float*)d_in[17]; const float* g3_bih0 = (const float*)d_in[18];
    const float* g3_whh0 = (const float*)d_in[19]; const float* g3_bhh0 = (const float*)d_in[20];
    const float* g3_wih  = (const float*)d_in[21]; const float* g3_bih  = (const float*)d_in[22];
    const float* g3_whh  = (const float*)d_in[23]; const float* g3_bhh  = (const float*)d_in[24];
    const float* d1w = (const float*)d_in[25]; const float* d1b = (const float*)d_in[26];
    const float* d2w = (const float*)d_in[27]; const float* d2b = (const float*)d_in[28];
    const float* d3w = (const float*)d_in[29]; const float* d3b = (const float*)d_in[30];

    float* wsf = (float*)d_ws;
    const size_t RINGS = (size_t)192 * DRING * 4096;
    const size_t B1SZ  = (size_t)96 * 128 * 128;
    const size_t SEQA  = (size_t)96 * 64 * 128;
    const int    SLOTN = 192 * FS;
    float* rings1 = wsf;
    float* rings2 = rings1 + RINGS;
    float* rings3 = rings2 + RINGS;
    float* B1     = rings3 + RINGS;
    float* B2     = B1 + B1SZ;
    float* seqA   = B2 + B1SZ;
    float* hFinal = seqA + SEQA;
    int*   flags  = (int*)(hFinal + 8192);
    int*   prb    = flags + (size_t)4 * SLOTN;
    float* XG     = (float*)(prb + (size_t)4 * SLOTN);   // 96*192*128 floats

    size_t zero_bytes = (B1SZ * 2 + SEQA + 8192) * sizeof(float)
                      + (size_t)8 * SLOTN * sizeof(int);
    (void)hipMemsetAsync(B1, 0, zero_bytes, stream);

    xprep_kernel<<<dim3(144), dim3(256), 0, stream>>>(x, seqA);

    // XG for pass1 (din=3, from host input)
    xg_kernel<<<dim3(96, 3), dim3(256), 0, stream>>>(g1_wih0, seqA, XG, 192, 3, 8192);

    PassArgs P1 = {g1_wih0, g1_bih0, g1_whh0, g1_bhh0, g1_wih, g1_bih, g1_whh, g1_bhh,
                   0, 96, seqA, 8192, B1, nullptr, rings1, flags + 0 * SLOTN, prb + 0 * SLOTN,
                   XG, nullptr, 0, 0, 1};
    PassArgs P2 = {g2_wih0, g2_bih0, g2_whh0, g2_bhh0, g2_wih, g2_bih, g2_whh, g2_bhh,
                   0, 48, B1, 16384, B2, nullptr, rings2, flags + 1 * SLOTN, prb + 1 * SLOTN,
                   nullptr, flags + 0 * SLOTN, 95 * 2, 2, 1};
    PassArgs P3 = {g2_wih0, g2_bih0, g2_whh0, g2_bhh0, g2_wih, g2_bih, g2_whh, g2_bhh,
                   48, 48, B2, 16384, B1, nullptr, rings3, flags + 2 * SLOTN, prb + 2 * SLOTN,
                   nullptr, flags + 1 * SLOTN, 47 * 4, 4, 0};
    fused_kernel<<<dim3(192), dim3(TPB), 0, stream>>>(P1, P2, P3);

    // XG for pass4 (din=128, from B1 written by fused pass3)
    xg_kernel<<<dim3(96, 3), dim3(256), 0, stream>>>(g3_wih0, B1, XG, 192, 128, 16384);

    PassArgs P4 = {g3_wih0, g3_bih0, g3_whh0, g3_bhh0, g3_wih, g3_bih, g3_whh, g3_bhh,
                   0, 96, B1, 16384, nullptr, hFinal, rings1, flags + 3 * SLOTN, prb + 3 * SLOTN,
                   XG, nullptr, 0, 0, 0};
    pass4_kernel<<<dim3(192), dim3(TPB), 0, stream>>>(P4);

    head_kernel<<<dim3(128), dim3(256), 0, stream>>>(hFinal, d1w, d1b, d2w, d2b, d3w, d3b,
                                                     (float*)d_out);
}

// Round 10
// 8004.410 us; speedup vs baseline: 1.4186x; 1.0130x over previous
//
#include <hip/hip_runtime.h>

// GRU_781684048417 — round 15: fuse ALL four passes into one persistent kernel.
//
// r14 (fuse 1-3) won: 9.18 -> 8.11ms.  Pass 4 was still a serial dispatch
// (~3ms, mostly fill) gated on the XG precompute (needs all of B1).  This
// round: phase 4 joins the fused kernel; its l==0 (2 blocks) does a real
// din=128 ih gemm: CP-stage B1[t] (gated on done3[l=47] flags, the proven
// r14 boundary pattern) + per-step HALF-matrix wt_ih restage (49KB, L2-hot;
// resident half alternates).  Phase-4 rings/flags/probes use private
// regions; mapping identical to standalone pass4.  B1 hazards are
// chain-enforced.  Per-step protocol byte-identical to r13/r14.

#define TPB 512
#define DRING 4
#define FS 64
#define PROBE_A 0x51CAFE77
#define PROBE_B 0x2B2B2B2B

typedef float vf4 __attribute__((ext_vector_type(4)));

__device__ __forceinline__ float sigmoid_f(float x) { return 1.0f / (1.0f + __expf(-x)); }
__device__ __forceinline__ float tanh_f(float x)    { return 1.0f - 2.0f / (__expf(2.0f * x) + 1.0f); }

__device__ __forceinline__ int cp_load(const int* p) {
    return __hip_atomic_load(p, __ATOMIC_RELAXED, __HIP_MEMORY_SCOPE_AGENT);
}
__device__ __forceinline__ void cp_store(int* p, int v) {
    __hip_atomic_store(p, v, __ATOMIC_RELAXED, __HIP_MEMORY_SCOPE_AGENT);
}
__device__ __forceinline__ int cp_poll_nz(const int* p) {
    int v;
    while (!(v = cp_load(p))) __builtin_amdgcn_s_sleep(8);
    return v;
}

__device__ __forceinline__ void vmwait0() { asm volatile("s_waitcnt vmcnt(0)" ::: "memory"); }
__device__ __forceinline__ int ld_l2_b32_wait(const int* p) {
    int r;
    asm volatile("global_load_dword %0, %1, off sc0\n\t"
                 "s_waitcnt vmcnt(0)"
                 : "=v"(r) : "v"(p) : "memory");
    return r;
}
__device__ __forceinline__ void st_l2_b32(int* p, int v) {
    asm volatile("global_store_dword %0, %1, off sc0" :: "v"(p), "v"(v) : "memory");
}
__device__ __forceinline__ void st_l2_f4(float* p, float4 v) {
    vf4 w; w[0] = v.x; w[1] = v.y; w[2] = v.z; w[3] = v.w;
    asm volatile("global_store_dwordx4 %0, %1, off sc0" :: "v"(p), "v"(w) : "memory");
}
__device__ __forceinline__ void ld_l2_2xf4(const float* p0, const float* p1,
                                           vf4& a, vf4& b) {
    asm volatile("global_load_dwordx4 %0, %2, off sc0\n\t"
                 "global_load_dwordx4 %1, %3, off sc0\n\t"
                 "s_waitcnt vmcnt(0)"
                 : "=&v"(a), "=&v"(b)
                 : "v"(p0), "v"(p1)
                 : "memory");
}
__device__ __forceinline__ void ld_l2_4xf4(const float* p0, const float* p1,
                                           const float* p2, const float* p3,
                                           vf4& a, vf4& b, vf4& c, vf4& d) {
    asm volatile("global_load_dwordx4 %0, %4, off sc0\n\t"
                 "global_load_dwordx4 %1, %5, off sc0\n\t"
                 "global_load_dwordx4 %2, %6, off sc0\n\t"
                 "global_load_dwordx4 %3, %7, off sc0\n\t"
                 "s_waitcnt vmcnt(0)"
                 : "=&v"(a), "=&v"(b), "=&v"(c), "=&v"(d)
                 : "v"(p0), "v"(p1), "v"(p2), "v"(p3)
                 : "memory");
}

__device__ __forceinline__ void st_cp_f4(float* p, float4 v) {
    vf4 w; w[0] = v.x; w[1] = v.y; w[2] = v.z; w[3] = v.w;
    asm volatile("global_store_dwordx4 %0, %1, off sc0 sc1" :: "v"(p), "v"(w) : "memory");
}
__device__ __forceinline__ void ld_cp_2xf4(const float* p0, const float* p1,
                                           vf4& a, vf4& b) {
    asm volatile("global_load_dwordx4 %0, %2, off sc0 sc1\n\t"
                 "global_load_dwordx4 %1, %3, off sc0 sc1\n\t"
                 "s_waitcnt vmcnt(0)"
                 : "=&v"(a), "=&v"(b)
                 : "v"(p0), "v"(p1)
                 : "memory");
}
__device__ __forceinline__ void ld_cp_4xf4(const float* p0, const float* p1,
                                           const float* p2, const float* p3,
                                           vf4& a, vf4& b, vf4& c, vf4& d) {
    asm volatile("global_load_dwordx4 %0, %4, off sc0 sc1\n\t"
                 "global_load_dwordx4 %1, %5, off sc0 sc1\n\t"
                 "global_load_dwordx4 %2, %6, off sc0 sc1\n\t"
                 "global_load_dwordx4 %3, %7, off sc0 sc1\n\t"
                 "s_waitcnt vmcnt(0)"
                 : "=&v"(a), "=&v"(b), "=&v"(c), "=&v"(d)
                 : "v"(p0), "v"(p1), "v"(p2), "v"(p3)
                 : "memory");
}

__device__ __forceinline__ void wait_flag(int* fp, int tgt, bool fast) {
    if (fast) { while (ld_l2_b32_wait(fp) < tgt) __builtin_amdgcn_s_sleep(1); }
    else      { while (cp_load(fp) < tgt)        __builtin_amdgcn_s_sleep(2); }
}

struct PassArgs {
    const float* wih0; const float* bih0; const float* whh0; const float* bhh0;
    const float* wihA; const float* bihA; const float* whhA; const float* bhhA;
    int firstLayer;
    int NL;
    const float* seqIn;
    long seqTs;
    float* seqOut;
    float* hFinal;
    float* rings;
    int* done;
    int* prb;
    const float* xg;         // non-null => l==0 uses precomputed ih gates
    const int* prevDone;     // non-null => in-kernel boundary for l==0
    int prevBase;
    int prevN;
    int cpSeqOut;
};

template<int STACK>
__device__ void pass_body(const PassArgs& A, int l, int part, int tid,
                          float* wt_hh, float* wt_ih, float* atile, float* hbuf)
{
    constexpr int NG    = (STACK == 2) ? 96 : 192;
    constexpr int KH    = (STACK == 2) ? 128 : 64;
    constexpr int KI    = (STACK == 2) ? 128 : 64;
    constexpr int PARTS = (STACK == 2) ? 4 : 2;
    constexpr int JS    = NG / 3;
    constexpr int NGG   = NG / 6;
    constexpr int BGN   = TPB / NGG;
    constexpr int WROW  = NGG * 12;
    constexpr int XGT   = (STACK == 2) ? 384 * 128 : 192 * 128;

    const int rb = l * PARTS + part;
    const int gl = A.firstLayer + l;
    const bool useXG = (A.xg != nullptr);

    const int gg = tid / BGN;
    const int bg = tid % BGN;
    const int jl0 = 2 * gg, jl1 = 2 * gg + 1;
    const int b0 = 4 * bg;

    const float *wih, *bih, *whh, *bhh;
    if (gl == 0) { wih = A.wih0; bih = A.bih0; whh = A.whh0; bhh = A.bhh0; }
    else {
        const int wsz = (STACK == 2) ? 384 * 128 : 192 * 64;
        const int bs  = (STACK == 2) ? 384 : 192;
        wih = A.wihA + (size_t)(gl - 1) * wsz; bih = A.bihA + (size_t)(gl - 1) * bs;
        whh = A.whhA + (size_t)(gl - 1) * wsz; bhh = A.bhhA + (size_t)(gl - 1) * bs;
    }
    const int din = (gl == 0) ? ((STACK == 1) ? 3 : ((STACK == 2) ? 64 : 128))
                              : ((STACK == 2) ? 128 : 64);
    // stacks1/3 l==0 without XG => din=128 handled as two 64-k halves
    const bool dualIH = (STACK != 2) && (l == 0) && !useXG;

    auto grow = [&](int r) -> int {
        if (STACK == 2) return (r >> 5) * 128 + 32 * part + (r & 31);
        return r;
    };

    for (int i = tid; i < NG * KH; i += TPB) {
        int r = i / KH, k = i - r * KH;
        int g = r / JS, j = r - g * JS;
        wt_hh[(k >> 1) * WROW + (j >> 1) * 12 + (k & 1) * 6 + g * 2 + (j & 1)]
            = whh[(size_t)grow(r) * KH + k];
    }
    if (l > 0 || !useXG) {
        for (int i = tid; i < NG * KI; i += TPB) {
            int r = i / KI, k = i - r * KI;
            int g = r / JS, j = r - g * JS;
            wt_ih[(k >> 1) * WROW + (j >> 1) * 12 + (k & 1) * 6 + g * 2 + (j & 1)]
                = (k < din) ? wih[(size_t)grow(r) * din + k] : 0.0f;
        }
    }

    float bR[2], bZ[2], bNH[2], bNI[2];
#pragma unroll
    for (int jj = 0; jj < 2; ++jj) {
        int jl = jl0 + jj;
        bR[jj]  = bhh[grow(jl)]          + bih[grow(jl)];
        bZ[jj]  = bhh[grow(JS + jl)]     + bih[grow(JS + jl)];
        bNH[jj] = bhh[grow(2 * JS + jl)];
        bNI[jj] = bih[grow(2 * JS + jl)];
    }

    float hprev[2][4];
#pragma unroll
    for (int jj = 0; jj < 2; ++jj)
#pragma unroll
        for (int bb = 0; bb < 4; ++bb) hprev[jj][bb] = 0.0f;

    // ---------------- probes + link modes ----------------
    bool f_in = false, f_out = false, f_fl_self = false, f_fl_par = false, f_fl_child = false;
    {
        int* hsk = (int*)atile;
        const int NL = A.NL;
        if (STACK != 2) {
            if (tid == 0 && l < NL - 1) {
                int* rg = A.prb + (size_t)rb * FS;
                cp_store(rg, PROBE_A); vmwait0();
                (void)ld_l2_b32_wait(rg);
                cp_store(rg, PROBE_B); vmwait0();
                cp_store(rg + 1, 1);
            }
            if (tid == 1 && l > 0) {
                int* rg = A.prb + (size_t)((l - 1) * PARTS + part) * FS;
                (void)cp_poll_nz(rg + 1);
                int v = ld_l2_b32_wait(rg);
                cp_store(rg + 2, (v == PROBE_A) ? 2 : 1);
            }
            if (tid >= 8 && tid < 12) {
                int j = l - 2 + (tid - 8);
                hsk[tid - 8] = (j >= 0 && j < NL - 1)
                    ? cp_poll_nz(A.prb + (size_t)(j * PARTS + part) * FS + 2) : 0;
            }
        } else {
            if (part == 0 && tid < 4 && (tid > 0 || l < NL - 1)) {
                int* rg = A.prb + (size_t)(l * 4 + tid) * FS;
                cp_store(rg, PROBE_A); vmwait0();
                (void)ld_l2_b32_wait(rg);
                cp_store(rg, PROBE_B); vmwait0();
                cp_store(rg + 1, 1);
            }
            if (tid == 4 && (part != 0 || l > 0)) {
                int* rg = (part != 0) ? A.prb + (size_t)(l * 4 + part) * FS
                                      : A.prb + (size_t)((l - 1) * 4) * FS;
                (void)cp_poll_nz(rg + 1);
                int v = ld_l2_b32_wait(rg);
                cp_store(rg + 2, (v == PROBE_A) ? 2 : 1);
            }
            if (tid >= 8 && tid < 28) {
                int q = tid - 8, r = q >> 2, p = q & 3;
                int a = l - 2 + r;
                bool valid = (a >= 0 && a < NL) && (p > 0 || a < NL - 1);
                hsk[q] = valid ? cp_poll_nz(A.prb + (size_t)(a * 4 + p) * FS + 2) : 0;
            }
        }
        __syncthreads();
        if (STACK != 2) {
            const int NLl = A.NL;
            bool pp0 = hsk[0] == 2, pp1 = hsk[1] == 2, pp2 = hsk[2] == 2, pp3 = hsk[3] == 2;
            f_in       = (l > 0) && pp1;
            f_out      = (l == NLl - 1) || pp2;
            f_fl_self  = (l == 0 || pp1) && (l == NLl - 1 || pp2);
            f_fl_par   = (l > 0) && pp1 && (l < 2 || pp0);
            f_fl_child = (l < NLl - 1) && pp2 && (l + 2 >= NLl || pp3);
        } else {
            const int NLl = A.NL;
            bool S[5], T[4];
#pragma unroll
            for (int r = 0; r < 5; ++r)
                S[r] = hsk[r * 4 + 1] == 2 && hsk[r * 4 + 2] == 2 && hsk[r * 4 + 3] == 2;
#pragma unroll
            for (int r = 0; r < 4; ++r) T[r] = hsk[r * 4 + 0] == 2;
            f_out      = S[2] && (l == NLl - 1 || (S[3] && T[2]));
            f_in       = (l > 0) && S[1] && S[2] && T[1];
            f_fl_self  = S[2] && (l == 0 || (S[1] && T[1])) && (l == NLl - 1 || (S[3] && T[2]));
            f_fl_par   = (l > 0) && S[1] && S[2] && T[1] && (l < 2 || (S[0] && T[0]));
            f_fl_child = (l < NLl - 1) && S[2] && S[3] && T[2] && (l + 2 >= NLl || (S[4] && T[3]));
        }
        __syncthreads();
    }

    auto gemmP = [&](const float* wt, const float* at, int astride,
                     float (&accR)[2][4], float (&accZ)[2][4], float (&accN)[2][4]) {
#pragma unroll 2
        for (int k2 = 0; k2 < 32; ++k2) {
            const float* wr = wt + k2 * WROW + gg * 12;
            vf4 q0 = *(const vf4*)(wr);
            vf4 q1 = *(const vf4*)(wr + 4);
            vf4 q2 = *(const vf4*)(wr + 8);
            const float* ar = at + (2 * k2) * astride + b0;
            float4 a0v = *(const float4*)(ar);
            float4 a1v = *(const float4*)(ar + astride);
            float a0[4] = {a0v.x, a0v.y, a0v.z, a0v.w};
            float a1[4] = {a1v.x, a1v.y, a1v.z, a1v.w};
#pragma unroll
            for (int bb = 0; bb < 4; ++bb) {
                accR[0][bb] += q0.x * a0[bb];  accR[1][bb] += q0.y * a0[bb];
                accZ[0][bb] += q0.z * a0[bb];  accZ[1][bb] += q0.w * a0[bb];
                accN[0][bb] += q1.x * a0[bb];  accN[1][bb] += q1.y * a0[bb];
                accR[0][bb] += q1.z * a1[bb];  accR[1][bb] += q1.w * a1[bb];
                accZ[0][bb] += q2.x * a1[bb];  accZ[1][bb] += q2.y * a1[bb];
                accN[0][bb] += q2.z * a1[bb];  accN[1][bb] += q2.w * a1[bb];
            }
        }
    };

    auto stage2 = [&](int baseBlk, int slotT, int kt, bool fast) {
        const float* p[4];
#pragma unroll
        for (int q = 0; q < 4; ++q) {
            int u4 = tid + q * TPB, r = u4 >> 5, c4 = u4 & 31, kk = kt * 64 + r;
            p[q] = A.rings + ((size_t)(baseBlk + (kk >> 5)) * DRING + slotT) * 4096
                           + (kk & 31) * 128 + 4 * c4;
        }
        vf4 ta, tb, tc, td;
        if (fast) ld_l2_4xf4(p[0], p[1], p[2], p[3], ta, tb, tc, td);
        else      ld_cp_4xf4(p[0], p[1], p[2], p[3], ta, tb, tc, td);
        {
            int u4, r, c4;
            u4 = tid;           r = u4 >> 5; c4 = u4 & 31; *(vf4*)&atile[r * 128 + 4 * c4] = ta;
            u4 = tid + TPB;     r = u4 >> 5; c4 = u4 & 31; *(vf4*)&atile[r * 128 + 4 * c4] = tb;
            u4 = tid + 2 * TPB; r = u4 >> 5; c4 = u4 & 31; *(vf4*)&atile[r * 128 + 4 * c4] = tc;
            u4 = tid + 3 * TPB; r = u4 >> 5; c4 = u4 & 31; *(vf4*)&atile[r * 128 + 4 * c4] = td;
        }
    };

    // dual-IH staging: B1[t] half kt -> atile[64x64] via CP loads
    auto stageDual = [&](int t, int kt) {
        const float* srcb = A.seqIn + (size_t)t * A.seqTs + (size_t)kt * 64 * 128 + 64 * part;
        int i0 = tid, i1 = tid + TPB;
        const float* p0 = srcb + (i0 >> 4) * 128 + (i0 & 15) * 4;
        const float* p1 = srcb + (i1 >> 4) * 128 + (i1 & 15) * 4;
        vf4 a, b;
        ld_cp_2xf4(p0, p1, a, b);
        *(vf4*)&atile[(i0 >> 4) * 64 + (i0 & 15) * 4] = a;
        *(vf4*)&atile[(i1 >> 4) * 64 + (i1 & 15) * 4] = b;
    };

    int res = 0;   // resident wt_ih half for dualIH

    for (int t = 0; t < 96; ++t) {
        float accR[2][4] = {}, accZ[2][4] = {}, accNH[2][4] = {}, accNI[2][4] = {};

        if (STACK != 2) {
            if (t > 0) gemmP(wt_hh, hbuf, 64, accR, accZ, accNH);

            if (tid < 8) {
                int grp = tid >> 2, idx = tid & 3;
                int* fp = nullptr; int tgt = 0; bool fm = false;
                if (grp == 0) {
                    if (l > 0 && idx == part)
                        { fp = &A.done[((l - 1) * PARTS + idx) * FS]; tgt = t + 1; fm = f_fl_par; }
                    else if (l == 0 && A.prevDone && idx < A.prevN)
                        { fp = (int*)&A.prevDone[(A.prevBase + idx) * FS]; tgt = t + 1; fm = false; }
                }
                else { if (t >= DRING && l < A.NL - 1 && idx == part)
                       { fp = &A.done[((l + 1) * PARTS + idx) * FS]; tgt = t - DRING + 1; fm = f_fl_child; } }
                if (fp) wait_flag(fp, tgt, fm);
            }
            __syncthreads();

            if (l == 0 && useXG) {
                const float* xgp = A.xg + (size_t)t * XGT + 64 * part + b0;
                auto xgacc = [&](int row, float (&acc)[4]) {
                    float4 xv = *(const float4*)&xgp[(size_t)row * 128];
                    acc[0] += xv.x; acc[1] += xv.y; acc[2] += xv.z; acc[3] += xv.w;
                };
                xgacc(jl0, accR[0]);            xgacc(jl1, accR[1]);
                xgacc(JS + jl0, accZ[0]);       xgacc(JS + jl1, accZ[1]);
                xgacc(2 * JS + jl0, accNI[0]);  xgacc(2 * JS + jl1, accNI[1]);
            } else if (dualIH) {
                // half 1: resident weights + staged atile
                stageDual(t, res);
                __syncthreads();
                gemmP(wt_ih, atile, 64, accR, accZ, accNI);
                __syncthreads();
                // half 2: restage weights (49KB, L2-hot) + stage atile
                {
                    int kt2 = res ^ 1;
                    for (int i = tid; i < 192 * 64; i += TPB) {
                        int r = i >> 6, k = i & 63;
                        int g = r / JS, j = r - g * JS;
                        wt_ih[(k >> 1) * WROW + (j >> 1) * 12 + (k & 1) * 6 + g * 2 + (j & 1)]
                            = wih[(size_t)r * 128 + kt2 * 64 + k];
                    }
                    stageDual(t, kt2);
                }
                __syncthreads();
                gemmP(wt_ih, atile, 64, accR, accZ, accNI);
                res ^= 1;
            } else {
                const float* slot = A.rings + ((size_t)((l - 1) * PARTS + part) * DRING + (t & 3)) * 4096;
                vf4 ta, tb;
                if (f_in) ld_l2_2xf4(slot + 4 * tid, slot + 4 * (tid + TPB), ta, tb);
                else      ld_cp_2xf4(slot + 4 * tid, slot + 4 * (tid + TPB), ta, tb);
                *(vf4*)&atile[4 * tid] = ta;
                *(vf4*)&atile[4 * (tid + TPB)] = tb;
                __syncthreads();
                gemmP(wt_ih, atile, 64, accR, accZ, accNI);
            }
        } else {
            if (t > 0) {
                if (tid < 4 && tid != part)
                    wait_flag(&A.done[(l * 4 + tid) * FS], t, f_fl_self);
                __syncthreads();
                for (int kt = 0; kt < 2; ++kt) {
                    if (kt) __syncthreads();
                    stage2(l * 4, (t - 1) & 3, kt, f_out);
                    __syncthreads();
                    gemmP(wt_hh + kt * 32 * WROW, atile, 128, accR, accZ, accNH);
                }
            }

            if (tid < 8) {
                int grp = tid >> 2, idx = tid & 3;
                int* fp = nullptr; int tgt = 0; bool fm = false;
                if (grp == 0) {
                    if (l > 0) { fp = &A.done[((l - 1) * 4 + idx) * FS]; tgt = t + 1; fm = f_fl_par; }
                    else if (A.prevDone && idx < A.prevN)
                         { fp = (int*)&A.prevDone[(A.prevBase + idx) * FS]; tgt = t + 1; fm = false; }
                }
                else { if (t >= DRING && l < A.NL - 1)
                       { fp = &A.done[((l + 1) * 4 + idx) * FS]; tgt = t - DRING + 1; fm = f_fl_child; } }
                if (fp) wait_flag(fp, tgt, fm);
            }
            __syncthreads();

            if (l == 0 && useXG) {
                const float* xgp = A.xg + (size_t)t * XGT + b0;
                auto xgacc = [&](int row, float (&acc)[4]) {
                    float4 xv = *(const float4*)&xgp[(size_t)row * 128];
                    acc[0] += xv.x; acc[1] += xv.y; acc[2] += xv.z; acc[3] += xv.w;
                };
                xgacc(grow(jl0), accR[0]);            xgacc(grow(jl1), accR[1]);
                xgacc(grow(JS + jl0), accZ[0]);       xgacc(grow(JS + jl1), accZ[1]);
                xgacc(grow(2 * JS + jl0), accNI[0]);  xgacc(grow(2 * JS + jl1), accNI[1]);
            } else {
                const int nkt = (l == 0 && A.firstLayer == 0) ? 1 : 2;
                for (int kt = 0; kt < nkt; ++kt) {
                    if (kt) __syncthreads();
                    if (l == 0) {
                        const float* src = A.seqIn + (size_t)t * A.seqTs + (size_t)kt * 64 * 128;
                        if (A.prevDone) {
                            vf4 a, b, c, d;
                            ld_cp_4xf4(src + 4 * tid, src + 4 * (tid + TPB),
                                       src + 4 * (tid + 2 * TPB), src + 4 * (tid + 3 * TPB),
                                       a, b, c, d);
                            *(vf4*)&atile[4 * tid] = a;
                            *(vf4*)&atile[4 * (tid + TPB)] = b;
                            *(vf4*)&atile[4 * (tid + 2 * TPB)] = c;
                            *(vf4*)&atile[4 * (tid + 3 * TPB)] = d;
                        } else {
                            for (int i = tid; i < 2048; i += TPB)
                                *(float4*)&atile[4 * i] = *(const float4*)(src + 4 * i);
                        }
                    } else {
                        stage2((l - 1) * 4, t & 3, kt, f_in);
                    }
                    __syncthreads();
                    gemmP(wt_ih + kt * 32 * WROW, atile, 128, accR, accZ, accNI);
                }
            }
        }

        // ---- gates + h update + publish ----
        float4 hv[2];
#pragma unroll
        for (int jj = 0; jj < 2; ++jj) {
            float* hp = (float*)&hv[jj];
#pragma unroll
            for (int bb = 0; bb < 4; ++bb) {
                float r = sigmoid_f(accR[jj][bb] + bR[jj]);
                float z = sigmoid_f(accZ[jj][bb] + bZ[jj]);
                float n = tanh_f(accNI[jj][bb] + bNI[jj] + r * (accNH[jj][bb] + bNH[jj]));
                float h = (1.0f - z) * n + z * hprev[jj][bb];
                hprev[jj][bb] = h;
                hp[bb] = h;
            }
        }
        float* slot = A.rings + ((size_t)rb * DRING + (t & 3)) * 4096;
        if (STACK == 2) {
            if (f_out) {
                st_l2_f4(&slot[jl0 * 128 + b0], hv[0]);
                st_l2_f4(&slot[jl1 * 128 + b0], hv[1]);
            } else {
                st_cp_f4(&slot[jl0 * 128 + b0], hv[0]);
                st_cp_f4(&slot[jl1 * 128 + b0], hv[1]);
            }
            if (A.seqOut && l == A.NL - 1) {
                float* o0 = &A.seqOut[(size_t)t * 16384 + (32 * part + jl0) * 128 + b0];
                float* o1 = &A.seqOut[(size_t)t * 16384 + (32 * part + jl1) * 128 + b0];
                if (A.cpSeqOut) { st_cp_f4(o0, hv[0]); st_cp_f4(o1, hv[1]); }
                else            { *(float4*)o0 = hv[0]; *(float4*)o1 = hv[1]; }
            }
        } else {
            if (f_out) {
                st_l2_f4(&slot[jl0 * 64 + b0], hv[0]);
                st_l2_f4(&slot[jl1 * 64 + b0], hv[1]);
            } else {
                st_cp_f4(&slot[jl0 * 64 + b0], hv[0]);
                st_cp_f4(&slot[jl1 * 64 + b0], hv[1]);
            }
            *(float4*)&hbuf[jl0 * 64 + b0] = hv[0];
            *(float4*)&hbuf[jl1 * 64 + b0] = hv[1];
            if (A.seqOut && l == A.NL - 1) {
                float* o0 = &A.seqOut[(size_t)t * 16384 + jl0 * 128 + 64 * part + b0];
                float* o1 = &A.seqOut[(size_t)t * 16384 + jl1 * 128 + 64 * part + b0];
                if (A.cpSeqOut) { st_cp_f4(o0, hv[0]); st_cp_f4(o1, hv[1]); }
                else            { *(float4*)o0 = hv[0]; *(float4*)o1 = hv[1]; }
            }
            if (STACK == 3 && l == A.NL - 1 && t == 95 && A.hFinal) {
                *(float4*)&A.hFinal[jl0 * 128 + 64 * part + b0] = hv[0];
                *(float4*)&A.hFinal[jl1 * 128 + 64 * part + b0] = hv[1];
            }
        }
        vmwait0();
        __syncthreads();
        if (tid == 0) {
            if (f_fl_self) st_l2_b32(&A.done[rb * FS], t + 1);
            else           cp_store(&A.done[rb * FS], t + 1);
        }
    }
}

// All four passes fused: each block runs pass1 -> pass2 -> pass3 -> pass4 roles.
__global__ __launch_bounds__(TPB, 2) void fused_kernel(PassArgs P1, PassArgs P2,
                                                       PassArgs P3, PassArgs P4)
{
    __shared__ __align__(16) float wt_hh[12288];
    __shared__ __align__(16) float wt_ih[12288];
    __shared__ __align__(16) float atile[8192];
    __shared__ __align__(16) float hbuf[4096];

    const int tid  = threadIdx.x;
    const int bidx = blockIdx.x;
    const int l13  = 12 * (bidx & 7) + ((bidx >> 3) >> 1), p13 = (bidx >> 3) & 1;
    const int l2   = 6 * (bidx & 7) + ((bidx >> 3) >> 2),  p2  = (bidx >> 3) & 3;

    pass_body<1>(P1, l13, p13, tid, wt_hh, wt_ih, atile, hbuf);
    __syncthreads();
    pass_body<2>(P2, l2, p2, tid, wt_hh, wt_ih, atile, hbuf);
    __syncthreads();
    pass_body<2>(P3, l2, p2, tid, wt_hh, wt_ih, atile, hbuf);
    __syncthreads();
    pass_body<3>(P4, l13, p13, tid, wt_hh, wt_ih, atile, hbuf);
}

// XG[t][r][b] = sum_k W[r][k] * X[t][k][b]  (pass-1 layer-0 only, din=3)
__global__ __launch_bounds__(256) void xg_kernel(const float* __restrict__ W,
    const float* __restrict__ X, float* __restrict__ XG,
    int NGtot, int din, long xts)
{
    __shared__ float xs[16384];
    const int t = blockIdx.x, r0 = blockIdx.y * 64, tid = threadIdx.x;
    for (int i = tid; i < din * 128; i += 256)
        xs[i] = X[(size_t)t * xts + i];
    __syncthreads();
    const int rr = tid >> 2, bq = tid & 3;
    const int r = r0 + rr;
    vf4 acc[8];
#pragma unroll
    for (int j = 0; j < 8; ++j) acc[j] = (vf4){0.f, 0.f, 0.f, 0.f};
    for (int k = 0; k < din; ++k) {
        float w = W[(size_t)r * din + k];
        const float* xr = &xs[k * 128 + bq * 32];
#pragma unroll
        for (int j = 0; j < 8; ++j) {
            vf4 xv = *(const vf4*)(xr + 4 * j);
            acc[j] += w * xv;
        }
    }
    float* out = &XG[((size_t)t * NGtot + r) * 128 + bq * 32];
#pragma unroll
    for (int j = 0; j < 8; ++j) *(vf4*)(out + 4 * j) = acc[j];
}

__global__ void xprep_kernel(const float* __restrict__ x, float* __restrict__ seqA)
{
    int i = blockIdx.x * 256 + threadIdx.x;
    if (i < 128 * 96 * 3) {
        int b = i / 288, r = i - b * 288;
        int t = r / 3, k = r - 3 * t;
        seqA[(size_t)t * 8192 + k * 128 + b] = x[i];
    }
}

__global__ __launch_bounds__(256) void head_kernel(
    const float* __restrict__ hF,
    const float* __restrict__ d1w, const float* __restrict__ d1b,
    const float* __restrict__ d2w, const float* __restrict__ d2b,
    const float* __restrict__ d3w, const float* __restrict__ d3b,
    float* __restrict__ out)
{
    const int b = blockIdx.x, tid = threadIdx.x;
    __shared__ float h1[64], h2[32];
    if (tid < 64) {
        float s = d1b[tid];
        for (int k = 0; k < 64; ++k) s += d1w[tid * 64 + k] * hF[k * 128 + b];
        h1[tid] = fmaxf(s, 0.0f);
    }
    __syncthreads();
    if (tid < 32) {
        float s = d2b[tid];
        for (int k = 0; k < 64; ++k) s += d2w[tid * 64 + k] * h1[k];
        h2[tid] = fmaxf(s, 0.0f);
    }
    __syncthreads();
    if (tid < 250) {
        float s = d3b[tid];
        for (int k = 0; k < 32; ++k) s += d3w[tid * 32 + k] * h2[k];
        out[b * 250 + tid] = fmaxf(s, 0.0f);
    }
}

extern "C" void kernel_launch(void* const* d_in, const int* in_sizes, int n_in,
                              void* d_out, int out_size, void* d_ws, size_t ws_size,
                              hipStream_t stream)
{
    const float* x       = (const float*)d_in[0];
    const float* g1_wih0 = (const float*)d_in[1];  const float* g1_bih0 = (const float*)d_in[2];
    const float* g1_whh0 = (const float*)d_in[3];  const float* g1_bhh0 = (const float*)d_in[4];
    const float* g1_wih  = (const float*)d_in[5];  const float* g1_bih  = (const float*)d_in[6];
    const float* g1_whh  = (const float*)d_in[7];  const float* g1_bhh  = (const float*)d_in[8];
    const float* g2_wih0 = (const float*)d_in[9];  const float* g2_bih0 = (const float*)d_in[10];
    const float* g2_whh0 = (const float*)d_in[11]; const float* g2_bhh0 = (const float*)d_in[12];
    const float* g2_wih  = (const float*)d_in[13]; const float* g2_bih  = (const float*)d_in[14];
    const float* g2_whh  = (const float*)d_in[15]; const float* g2_bhh  = (const float*)d_in[16];
    const float* g3_wih0 = (const float*)d_in[17]; const float* g3_bih0 = (const float*)d_in[18];
    const float* g3_whh0 = (const float*)d_in[19]; const float* g3_bhh0 = (const float*)d_in[20];
    const float* g3_wih  = (const float*)d_in[21]; const float* g3_bih  = (const float*)d_in[22];
    const float* g3_whh  = (const float*)d_in[23]; const float* g3_bhh  = (const float*)d_in[24];
    const float* d1w = (const float*)d_in[25]; const float* d1b = (const float*)d_in[26];
    const float* d2w = (const float*)d_in[27]; const float* d2b = (const float*)d_in[28];
    const float* d3w = (const float*)d_in[29]; const float* d3b = (const float*)d_in[30];

    float* wsf = (float*)d_ws;
    const size_t RINGS = (size_t)192 * DRING * 4096;
    const size_t B1SZ  = (size_t)96 * 128 * 128;
    const size_t SEQA  = (size_t)96 * 64 * 128;
    const int    SLOTN = 192 * FS;
    float* rings1 = wsf;
    float* rings2 = rings1 + RINGS;
    float* rings3 = rings2 + RINGS;
    float* rings4 = rings3 + RINGS;
    float* B1     = rings4 + RINGS;
    float* B2     = B1 + B1SZ;
    float* seqA   = B2 + B1SZ;
    float* hFinal = seqA + SEQA;
    int*   flags  = (int*)(hFinal + 8192);
    int*   prb    = flags + (size_t)4 * SLOTN;
    float* XG     = (float*)(prb + (size_t)4 * SLOTN);

    size_t zero_bytes = (B1SZ * 2 + SEQA + 8192) * sizeof(float)
                      + (size_t)8 * SLOTN * sizeof(int);
    (void)hipMemsetAsync(B1, 0, zero_bytes, stream);

    xprep_kernel<<<dim3(144), dim3(256), 0, stream>>>(x, seqA);

    // XG for pass1 only (din=3, from host input)
    xg_kernel<<<dim3(96, 3), dim3(256), 0, stream>>>(g1_wih0, seqA, XG, 192, 3, 8192);

    PassArgs P1 = {g1_wih0, g1_bih0, g1_whh0, g1_bhh0, g1_wih, g1_bih, g1_whh, g1_bhh,
                   0, 96, seqA, 8192, B1, nullptr, rings1, flags + 0 * SLOTN, prb + 0 * SLOTN,
                   XG, nullptr, 0, 0, 1};
    PassArgs P2 = {g2_wih0, g2_bih0, g2_whh0, g2_bhh0, g2_wih, g2_bih, g2_whh, g2_bhh,
                   0, 48, B1, 16384, B2, nullptr, rings2, flags + 1 * SLOTN, prb + 1 * SLOTN,
                   nullptr, flags + 0 * SLOTN, 95 * 2, 2, 1};
    PassArgs P3 = {g2_wih0, g2_bih0, g2_whh0, g2_bhh0, g2_wih, g2_bih, g2_whh, g2_bhh,
                   48, 48, B2, 16384, B1, nullptr, rings3, flags + 2 * SLOTN, prb + 2 * SLOTN,
                   nullptr, flags + 1 * SLOTN, 47 * 4, 4, 1};
    PassArgs P4 = {g3_wih0, g3_bih0, g3_whh0, g3_bhh0, g3_wih, g3_bih, g3_whh, g3_bhh,
                   0, 96, B1, 16384, nullptr, hFinal, rings4, flags + 3 * SLOTN, prb + 3 * SLOTN,
                   nullptr, flags + 2 * SLOTN, 47 * 4, 4, 0};
    fused_kernel<<<dim3(192), dim3(TPB), 0, stream>>>(P1, P2, P3, P4);

    head_kernel<<<dim3(128), dim3(256), 0, stream>>>(hFinal, d1w, d1b, d2w, d2b, d3w, d3b,
                                                     (float*)d_out);
}